// Round 1
// baseline (1594.363 us; speedup 1.0000x reference)
//
#include <hip/hip_runtime.h>

#define NT 256
constexpr int HIDC = 64;

// ---------------- CSR build ----------------

__global__ void deg_kernel(const int* __restrict__ ei, int E, int* __restrict__ deg) {
    int i = blockIdx.x * blockDim.x + threadIdx.x;
    int stride = gridDim.x * blockDim.x;
    for (int e = i; e < E; e += stride) {
        int d = ei[E + e];  // dst row
        atomicAdd(&deg[d], 1);
    }
}

__global__ void invdeg_kernel(const int* __restrict__ deg, float* __restrict__ invd, int N) {
    int i = blockIdx.x * blockDim.x + threadIdx.x;
    if (i < N) invd[i] = 1.0f / (float)max(deg[i], 1);
}

// inclusive scan of deg into out1[i] (= csr_off[1+i]); per-block totals to btot
__global__ void scan_block(const int* __restrict__ deg, int* __restrict__ out1,
                           int* __restrict__ btot, int N) {
    __shared__ int sums[NT];
    int t = threadIdx.x, b = blockIdx.x;
    int base = b * NT * 4 + t * 4;
    int v[4];
    int s = 0;
#pragma unroll
    for (int j = 0; j < 4; j++) {
        int idx = base + j;
        v[j] = (idx < N) ? deg[idx] : 0;
        s += v[j];
    }
    sums[t] = s;
    __syncthreads();
    for (int off = 1; off < NT; off <<= 1) {
        int xv = 0;
        if (t >= off) xv = sums[t - off];
        __syncthreads();
        sums[t] += xv;
        __syncthreads();
    }
    int run = (t == 0) ? 0 : sums[t - 1];
#pragma unroll
    for (int j = 0; j < 4; j++) {
        run += v[j];
        int idx = base + j;
        if (idx < N) out1[idx] = run;
    }
    if (t == NT - 1) btot[b] = sums[NT - 1];
}

__global__ void scan_btot(const int* __restrict__ btot, int* __restrict__ boff, int nb) {
    if (threadIdx.x == 0 && blockIdx.x == 0) {
        int run = 0;
        for (int b = 0; b < nb; b++) { boff[b] = run; run += btot[b]; }
    }
}

__global__ void scan_add(int* __restrict__ out1, const int* __restrict__ boff, int N) {
    int i = blockIdx.x * blockDim.x + threadIdx.x;
    if (i < N) out1[i] += boff[i / (NT * 4)];
}

__global__ void copy_off(const int* __restrict__ csr_off, int* __restrict__ cursor, int N) {
    int i = blockIdx.x * blockDim.x + threadIdx.x;
    if (i < N) cursor[i] = csr_off[i];
}

__global__ void fill_csr(const int* __restrict__ ei, int E, int* __restrict__ cursor,
                         int* __restrict__ csr_src) {
    int i = blockIdx.x * blockDim.x + threadIdx.x;
    int stride = gridDim.x * blockDim.x;
    for (int e = i; e < E; e += stride) {
        int s = ei[e];
        int d = ei[E + e];
        int p = atomicAdd(&cursor[d], 1);
        csr_src[p] = s;
    }
}

// ---------------- feature pipeline ----------------

__global__ void pad_x(const float* __restrict__ x, float* __restrict__ xp, int N) {
    int i = blockIdx.x * blockDim.x + threadIdx.x;
    if (i < N * HIDC) {
        int n = i >> 6, c = i & 63;
        xp[i] = (c < 13) ? x[n * 13 + c] : 0.f;
    }
}

// one wave per node: gather+mean over CSR neighbors, then out = mean@Wl + b + x@Wr (+relu)
__global__ __launch_bounds__(256, 4) void sage_layer(
    const float* __restrict__ x, const int* __restrict__ off, const int* __restrict__ csr,
    const float* __restrict__ invd, const float* __restrict__ Wl, const float* __restrict__ bl,
    const float* __restrict__ Wr, float* __restrict__ y, int N, int din, int relu) {
    __shared__ float wl[64][65];
    __shared__ float wr[64][65];
    __shared__ float bs[64];
    int t = threadIdx.x;
    for (int i = t; i < 64 * 64; i += 256) {
        int k = i >> 6, j = i & 63;
        wl[k][j] = (k < din) ? Wl[k * 64 + j] : 0.f;
        wr[k][j] = (k < din) ? Wr[k * 64 + j] : 0.f;
    }
    if (t < 64) bs[t] = bl[t];
    __syncthreads();

    int lane = t & 63, wid = t >> 6;
    int n = blockIdx.x * 4 + wid;
    if (n >= N) return;

    int e0 = off[n], e1 = off[n + 1];
    float acc = 0.f;
    int e = e0;
    for (; e + 3 < e1; e += 4) {
        int s0 = csr[e], s1 = csr[e + 1], s2 = csr[e + 2], s3 = csr[e + 3];
        float a0 = x[s0 * 64 + lane];
        float a1 = x[s1 * 64 + lane];
        float a2 = x[s2 * 64 + lane];
        float a3 = x[s3 * 64 + lane];
        acc += a0 + a1 + a2 + a3;
    }
    for (; e < e1; e++) acc += x[csr[e] * 64 + lane];
    acc *= invd[n];

    float xv = x[n * 64 + lane];
    float out = bs[lane];
#pragma unroll
    for (int k = 0; k < 64; k++) {
        float a = __shfl(acc, k);
        float b = __shfl(xv, k);
        out += a * wl[k][lane] + b * wr[k][lane];
    }
    if (relu) out = fmaxf(out, 0.f);
    y[n * 64 + lane] = out;
}

// final layer: dout = 1
__global__ __launch_bounds__(256, 4) void sage_last(
    const float* __restrict__ x, const int* __restrict__ off, const int* __restrict__ csr,
    const float* __restrict__ invd, const float* __restrict__ Wl, const float* __restrict__ bl,
    const float* __restrict__ Wr, float* __restrict__ out, int N) {
    int t = threadIdx.x, lane = t & 63, wid = t >> 6;
    int n = blockIdx.x * 4 + wid;
    if (n >= N) return;

    int e0 = off[n], e1 = off[n + 1];
    float acc = 0.f;
    int e = e0;
    for (; e + 3 < e1; e += 4) {
        int s0 = csr[e], s1 = csr[e + 1], s2 = csr[e + 2], s3 = csr[e + 3];
        acc += x[s0 * 64 + lane] + x[s1 * 64 + lane] + x[s2 * 64 + lane] + x[s3 * 64 + lane];
    }
    for (; e < e1; e++) acc += x[csr[e] * 64 + lane];
    acc *= invd[n];

    float xv = x[n * 64 + lane];
    float p = acc * Wl[lane] + xv * Wr[lane];
#pragma unroll
    for (int o = 32; o > 0; o >>= 1) p += __shfl_xor(p, o);
    if (lane == 0) out[n] = p + bl[0];
}

// ---------------- launch ----------------

extern "C" void kernel_launch(void* const* d_in, const int* in_sizes, int n_in,
                              void* d_out, int out_size, void* d_ws, size_t ws_size,
                              hipStream_t stream) {
    const float* x0 = (const float*)d_in[0];
    const int* ei = (const int*)d_in[1];
    const float* Wl[4] = {(const float*)d_in[2], (const float*)d_in[5], (const float*)d_in[8],
                          (const float*)d_in[11]};
    const float* bl[4] = {(const float*)d_in[3], (const float*)d_in[6], (const float*)d_in[9],
                          (const float*)d_in[12]};
    const float* Wr[4] = {(const float*)d_in[4], (const float*)d_in[7], (const float*)d_in[10],
                          (const float*)d_in[13]};
    float* out = (float*)d_out;

    const int N = in_sizes[0] / 13;
    const int E = in_sizes[1] / 2;
    const int NB = (N + NT * 4 - 1) / (NT * 4);

    // workspace carve (256B aligned)
    char* w = (char*)d_ws;
    auto carve = [&](size_t bytes) {
        void* p = (void*)w;
        w += (bytes + 255) & ~size_t(255);
        return p;
    };
    int* deg = (int*)carve((size_t)N * 4);
    int* csr_off = (int*)carve((size_t)(N + 1) * 4);
    int* cursor = (int*)carve((size_t)N * 4);
    int* btot = (int*)carve((size_t)NB * 4);
    int* boff = (int*)carve((size_t)NB * 4);
    int* csr_src = (int*)carve((size_t)E * 4);
    float* invd = (float*)carve((size_t)N * 4);
    float* xa = (float*)carve((size_t)N * 64 * 4);
    float* xb = (float*)carve((size_t)N * 64 * 4);

    hipMemsetAsync(deg, 0, (size_t)N * 4, stream);
    hipMemsetAsync(csr_off, 0, 4, stream);  // csr_off[0] = 0

    deg_kernel<<<2048, NT, 0, stream>>>(ei, E, deg);
    invdeg_kernel<<<(N + NT - 1) / NT, NT, 0, stream>>>(deg, invd, N);
    scan_block<<<NB, NT, 0, stream>>>(deg, csr_off + 1, btot, N);
    scan_btot<<<1, 64, 0, stream>>>(btot, boff, NB);
    scan_add<<<(N + NT - 1) / NT, NT, 0, stream>>>(csr_off + 1, boff, N);
    copy_off<<<(N + NT - 1) / NT, NT, 0, stream>>>(csr_off, cursor, N);
    fill_csr<<<2048, NT, 0, stream>>>(ei, E, cursor, csr_src);

    pad_x<<<(N * HIDC + NT - 1) / NT, NT, 0, stream>>>(x0, xa, N);

    int nblk = (N + 3) / 4;
    sage_layer<<<nblk, NT, 0, stream>>>(xa, csr_off, csr_src, invd, Wl[0], bl[0], Wr[0], xb, N, 13, 1);
    sage_layer<<<nblk, NT, 0, stream>>>(xb, csr_off, csr_src, invd, Wl[1], bl[1], Wr[1], xa, N, 64, 1);
    sage_layer<<<nblk, NT, 0, stream>>>(xa, csr_off, csr_src, invd, Wl[2], bl[2], Wr[2], xb, N, 64, 1);
    sage_last<<<nblk, NT, 0, stream>>>(xb, csr_off, csr_src, invd, Wl[3], bl[3], Wr[3], out, N);
}

// Round 2
// 1075.350 us; speedup vs baseline: 1.4826x; 1.4826x over previous
//
#include <hip/hip_runtime.h>

#define NT 256

// ---------------- CSR build ----------------

__global__ void deg_kernel(const int* __restrict__ ei, int E, int* __restrict__ deg) {
    int i = blockIdx.x * blockDim.x + threadIdx.x;
    int stride = gridDim.x * blockDim.x;
    for (int e = i; e < E; e += stride) atomicAdd(&deg[ei[E + e]], 1);
}

__global__ void invdeg_kernel(const int* __restrict__ deg, float* __restrict__ invd, int N) {
    int i = blockIdx.x * blockDim.x + threadIdx.x;
    if (i < N) invd[i] = 1.0f / (float)max(deg[i], 1);
}

__global__ void scan_block(const int* __restrict__ deg, int* __restrict__ out1,
                           int* __restrict__ btot, int N) {
    __shared__ int sums[NT];
    int t = threadIdx.x, b = blockIdx.x;
    int base = b * NT * 4 + t * 4;
    int v[4];
    int s = 0;
#pragma unroll
    for (int j = 0; j < 4; j++) {
        int idx = base + j;
        v[j] = (idx < N) ? deg[idx] : 0;
        s += v[j];
    }
    sums[t] = s;
    __syncthreads();
    for (int off = 1; off < NT; off <<= 1) {
        int xv = 0;
        if (t >= off) xv = sums[t - off];
        __syncthreads();
        sums[t] += xv;
        __syncthreads();
    }
    int run = (t == 0) ? 0 : sums[t - 1];
#pragma unroll
    for (int j = 0; j < 4; j++) {
        run += v[j];
        int idx = base + j;
        if (idx < N) out1[idx] = run;
    }
    if (t == NT - 1) btot[b] = sums[NT - 1];
}

__global__ void scan_btot(const int* __restrict__ btot, int* __restrict__ boff, int nb) {
    if (threadIdx.x == 0 && blockIdx.x == 0) {
        int run = 0;
        for (int b = 0; b < nb; b++) { boff[b] = run; run += btot[b]; }
    }
}

__global__ void scan_add(int* __restrict__ out1, const int* __restrict__ boff, int N) {
    int i = blockIdx.x * blockDim.x + threadIdx.x;
    if (i < N) out1[i] += boff[i / (NT * 4)];
}

__global__ void copy_off(const int* __restrict__ csr_off, int* __restrict__ cursor, int N) {
    int i = blockIdx.x * blockDim.x + threadIdx.x;
    if (i < N) cursor[i] = csr_off[i];
}

__global__ void fill_csr(const int* __restrict__ ei, int E, int* __restrict__ cursor,
                         int* __restrict__ csr_src) {
    int i = blockIdx.x * blockDim.x + threadIdx.x;
    int stride = gridDim.x * blockDim.x;
    for (int e = i; e < E; e += stride) {
        int s = ei[e];
        int d = ei[E + e];
        int p = atomicAdd(&cursor[d], 1);
        csr_src[p] = s;
    }
}

// ---------------- feature pipeline ----------------

// pack x [N,13] -> [N,16] zero-padded
__global__ void pad_x16(const float* __restrict__ x, float* __restrict__ xp, int N) {
    int i = blockIdx.x * blockDim.x + threadIdx.x;
    if (i < N * 16) {
        int n = i >> 4, c = i & 15;
        xp[i] = (c < 13) ? x[n * 13 + c] : 0.f;
    }
}

// layer 0: 16-ch gather (4 edges per wave-iter), din=16 matmul to 64
__global__ __launch_bounds__(512) void sage_layer0(
    const float* __restrict__ x16, const int* __restrict__ off, const int* __restrict__ csr,
    const float* __restrict__ invd, const float* __restrict__ Wl, const float* __restrict__ bl,
    const float* __restrict__ Wr, float* __restrict__ y, int N) {
    __shared__ float wl[16][64];
    __shared__ float wr[16][64];
    __shared__ float bs[64];
    int t = threadIdx.x;
    for (int i = t; i < 16 * 64; i += 512) {
        int k = i >> 6, j = i & 63;
        wl[k][j] = (k < 13) ? Wl[k * 64 + j] : 0.f;
        wr[k][j] = (k < 13) ? Wr[k * 64 + j] : 0.f;
    }
    if (t < 64) bs[t] = bl[t];
    __syncthreads();

    int lane = t & 63, wid = t >> 6;
    int n = blockIdx.x * 8 + wid;
    if (n >= N) return;

    int e0 = off[n], e1 = off[n + 1];
    int g = lane >> 4, c = lane & 15;
    float acc = 0.f;
    int e = e0;
    for (; e + 7 < e1; e += 8) {
        int s0 = csr[e + g];
        int s1 = csr[e + 4 + g];
        acc += x16[s0 * 16 + c] + x16[s1 * 16 + c];
    }
    for (; e + 3 < e1; e += 4) acc += x16[csr[e + g] * 16 + c];
    if (e + g < e1) acc += x16[csr[e + g] * 16 + c];

    // reduce the 4 groups -> every lane holds total for channel c
    acc += __shfl_xor(acc, 16);
    acc += __shfl_xor(acc, 32);
    acc *= invd[n];

    float xv = x16[n * 16 + c];
    float out = bs[lane];
#pragma unroll
    for (int k = 0; k < 16; k++) {
        float a = __shfl(acc, k);
        float b = __shfl(xv, k);
        out += a * wl[k][lane] + b * wr[k][lane];
    }
    y[n * 64 + lane] = fmaxf(out, 0.f);
}

// middle layers: 64-wide gather, 64x64 matmuls, relu
__global__ __launch_bounds__(512) void sage_layer(
    const float* __restrict__ x, const int* __restrict__ off, const int* __restrict__ csr,
    const float* __restrict__ invd, const float* __restrict__ Wl, const float* __restrict__ bl,
    const float* __restrict__ Wr, float* __restrict__ y, int N) {
    __shared__ float wl[64][64];
    __shared__ float wr[64][64];
    __shared__ float bs[64];
    int t = threadIdx.x;
    for (int i = t; i < 64 * 64; i += 512) {
        int k = i >> 6, j = i & 63;
        wl[k][j] = Wl[i];
        wr[k][j] = Wr[i];
    }
    if (t < 64) bs[t] = bl[t];
    __syncthreads();

    int lane = t & 63, wid = t >> 6;
    int n = blockIdx.x * 8 + wid;
    if (n >= N) return;

    float xv = x[n * 64 + lane];  // issue own-feature load early
    int e0 = off[n], e1 = off[n + 1];
    float acc = 0.f;
    int e = e0;
    for (; e + 7 < e1; e += 8) {
        int s[8];
#pragma unroll
        for (int j = 0; j < 8; j++) s[j] = csr[e + j];
        float a[8];
#pragma unroll
        for (int j = 0; j < 8; j++) a[j] = x[s[j] * 64 + lane];
#pragma unroll
        for (int j = 0; j < 8; j++) acc += a[j];
    }
    for (; e < e1; e++) acc += x[csr[e] * 64 + lane];
    acc *= invd[n];

    float out = bs[lane];
#pragma unroll
    for (int k = 0; k < 64; k++) {
        float a = __shfl(acc, k);
        float b = __shfl(xv, k);
        out += a * wl[k][lane] + b * wr[k][lane];
    }
    y[n * 64 + lane] = fmaxf(out, 0.f);
}

// project x3 -> scalars s3 = x3.Wl3, r3 = x3.Wr3 + b3 (one wave per node)
__global__ __launch_bounds__(512) void proj_last(
    const float* __restrict__ x, const float* __restrict__ Wl, const float* __restrict__ bl,
    const float* __restrict__ Wr, float* __restrict__ s3, float* __restrict__ r3, int N) {
    int t = threadIdx.x, lane = t & 63, wid = t >> 6;
    int n = blockIdx.x * 8 + wid;
    if (n >= N) return;
    float xv = x[n * 64 + lane];
    float p = xv * Wl[lane];
    float q = xv * Wr[lane];
#pragma unroll
    for (int o = 32; o > 0; o >>= 1) {
        p += __shfl_xor(p, o);
        q += __shfl_xor(q, o);
    }
    if (lane == 0) {
        s3[n] = p;
        r3[n] = q + bl[0];
    }
}

// final: scalar gather from L2-resident s3 (400 KB)
__global__ void sage_last_scalar(
    const float* __restrict__ s3, const float* __restrict__ r3, const int* __restrict__ off,
    const int* __restrict__ csr, const float* __restrict__ invd, float* __restrict__ out, int N) {
    int n = blockIdx.x * blockDim.x + threadIdx.x;
    if (n >= N) return;
    int e0 = off[n], e1 = off[n + 1];
    float acc = 0.f;
    int e = e0;
    for (; e + 3 < e1; e += 4) {
        float a0 = s3[csr[e]], a1 = s3[csr[e + 1]], a2 = s3[csr[e + 2]], a3 = s3[csr[e + 3]];
        acc += a0 + a1 + a2 + a3;
    }
    for (; e < e1; e++) acc += s3[csr[e]];
    out[n] = acc * invd[n] + r3[n];
}

// ---------------- launch ----------------

extern "C" void kernel_launch(void* const* d_in, const int* in_sizes, int n_in,
                              void* d_out, int out_size, void* d_ws, size_t ws_size,
                              hipStream_t stream) {
    const float* x0 = (const float*)d_in[0];
    const int* ei = (const int*)d_in[1];
    const float* Wl[4] = {(const float*)d_in[2], (const float*)d_in[5], (const float*)d_in[8],
                          (const float*)d_in[11]};
    const float* bl[4] = {(const float*)d_in[3], (const float*)d_in[6], (const float*)d_in[9],
                          (const float*)d_in[12]};
    const float* Wr[4] = {(const float*)d_in[4], (const float*)d_in[7], (const float*)d_in[10],
                          (const float*)d_in[13]};
    float* out = (float*)d_out;

    const int N = in_sizes[0] / 13;
    const int E = in_sizes[1] / 2;
    const int NB = (N + NT * 4 - 1) / (NT * 4);

    char* w = (char*)d_ws;
    auto carve = [&](size_t bytes) {
        void* p = (void*)w;
        w += (bytes + 255) & ~size_t(255);
        return p;
    };
    int* deg = (int*)carve((size_t)N * 4);
    int* csr_off = (int*)carve((size_t)(N + 1) * 4);
    int* cursor = (int*)carve((size_t)N * 4);
    int* btot = (int*)carve((size_t)NB * 4);
    int* boff = (int*)carve((size_t)NB * 4);
    int* csr_src = (int*)carve((size_t)E * 4);
    float* invd = (float*)carve((size_t)N * 4);
    float* x16 = (float*)carve((size_t)N * 16 * 4);
    float* xa = (float*)carve((size_t)N * 64 * 4);
    float* xb = (float*)carve((size_t)N * 64 * 4);
    float* s3 = (float*)carve((size_t)N * 4);
    float* r3 = (float*)carve((size_t)N * 4);

    hipMemsetAsync(deg, 0, (size_t)N * 4, stream);
    hipMemsetAsync(csr_off, 0, 4, stream);

    deg_kernel<<<2048, NT, 0, stream>>>(ei, E, deg);
    invdeg_kernel<<<(N + NT - 1) / NT, NT, 0, stream>>>(deg, invd, N);
    scan_block<<<NB, NT, 0, stream>>>(deg, csr_off + 1, btot, N);
    scan_btot<<<1, 64, 0, stream>>>(btot, boff, NB);
    scan_add<<<(N + NT - 1) / NT, NT, 0, stream>>>(csr_off + 1, boff, N);
    copy_off<<<(N + NT - 1) / NT, NT, 0, stream>>>(csr_off, cursor, N);
    fill_csr<<<2048, NT, 0, stream>>>(ei, E, cursor, csr_src);

    pad_x16<<<(N * 16 + NT - 1) / NT, NT, 0, stream>>>(x0, x16, N);

    int nblk8 = (N + 7) / 8;
    sage_layer0<<<nblk8, 512, 0, stream>>>(x16, csr_off, csr_src, invd, Wl[0], bl[0], Wr[0], xa, N);
    sage_layer<<<nblk8, 512, 0, stream>>>(xa, csr_off, csr_src, invd, Wl[1], bl[1], Wr[1], xb, N);
    sage_layer<<<nblk8, 512, 0, stream>>>(xb, csr_off, csr_src, invd, Wl[2], bl[2], Wr[2], xa, N);
    proj_last<<<nblk8, 512, 0, stream>>>(xa, Wl[3], bl[3], Wr[3], s3, r3, N);
    sage_last_scalar<<<(N + NT - 1) / NT, NT, 0, stream>>>(s3, r3, csr_off, csr_src, invd, out, N);
}

// Round 3
// 714.601 us; speedup vs baseline: 2.2311x; 1.5048x over previous
//
#include <hip/hip_runtime.h>

#define NT 256
#define NPB 256        // nodes per bucket (dst >> 8)
#define MAXBUK 512     // LDS-side padding for bucket arrays
#define A3_TILE 4096   // edges per partition block (256 thr x 16)

// ---------------- bucketed CSR build ----------------

__global__ __launch_bounds__(256) void bucket_hist(const int* __restrict__ ei, int E,
                                                   int* __restrict__ bcnt, int nbuk) {
    __shared__ int h[MAXBUK];
    int t = threadIdx.x;
    for (int i = t; i < MAXBUK; i += 256) h[i] = 0;
    __syncthreads();
    int i0 = blockIdx.x * 256 + t;
    int stride = gridDim.x * 256;
    for (int e = i0; e < E; e += stride) atomicAdd(&h[ei[E + e] >> 8], 1);
    __syncthreads();
    for (int b = t; b < nbuk; b += 256)
        if (h[b]) atomicAdd(&bcnt[b], h[b]);
}

__global__ __launch_bounds__(512) void bucket_scan(const int* __restrict__ bcnt,
                                                   int* __restrict__ bboff, int* __restrict__ bcur,
                                                   int nbuk, int* __restrict__ csr_off, int N,
                                                   int E) {
    __shared__ int s[512];
    int t = threadIdx.x;
    s[t] = (t < nbuk) ? bcnt[t] : 0;
    __syncthreads();
    for (int off = 1; off < 512; off <<= 1) {
        int v = 0;
        if (t >= off) v = s[t - off];
        __syncthreads();
        s[t] += v;
        __syncthreads();
    }
    int excl = (t == 0) ? 0 : s[t - 1];
    if (t <= nbuk) {
        bboff[t] = excl;
        if (t < nbuk) bcur[t] = excl;
    }
    if (t == 0) csr_off[N] = E;
}

__global__ __launch_bounds__(256) void partition(const int* __restrict__ ei, int E,
                                                 int* __restrict__ bcur,
                                                 unsigned int* __restrict__ pairs) {
    __shared__ int h[MAXBUK];
    __shared__ int base[MAXBUK];
    int t = threadIdx.x;
    for (int i = t; i < MAXBUK; i += 256) h[i] = 0;
    __syncthreads();
    int e0 = blockIdx.x * A3_TILE;
    int src[16], dst[16];
#pragma unroll
    for (int j = 0; j < 16; j++) {
        int e = e0 + j * 256 + t;
        if (e < E) {
            src[j] = ei[e];
            dst[j] = ei[E + e];
            atomicAdd(&h[dst[j] >> 8], 1);
        } else {
            dst[j] = -1;
        }
    }
    __syncthreads();
    for (int b = t; b < MAXBUK; b += 256) {
        int c = h[b];
        base[b] = c ? atomicAdd(&bcur[b], c) : 0;
        h[b] = 0;  // becomes local cursor
    }
    __syncthreads();
#pragma unroll
    for (int j = 0; j < 16; j++) {
        if (dst[j] >= 0) {
            int bkt = dst[j] >> 8;
            int r = atomicAdd(&h[bkt], 1);
            pairs[base[bkt] + r] = ((unsigned)(dst[j] & (NPB - 1)) << 24) | (unsigned)src[j];
        }
    }
}

__global__ __launch_bounds__(512) void build_bucket(const unsigned int* __restrict__ pairs,
                                                    const int* __restrict__ bboff,
                                                    int* __restrict__ csr_off,
                                                    int* __restrict__ csr_src,
                                                    float* __restrict__ invd, int N) {
    __shared__ int hist[NPB];
    __shared__ int ssum[NPB];
    __shared__ int cur[NPB];
    int b = blockIdx.x, t = threadIdx.x;
    int gb0 = bboff[b], gb1 = bboff[b + 1];
    int nb0 = b << 8;
    int nn = min(NPB, N - nb0);
    for (int i = t; i < NPB; i += 512) hist[i] = 0;
    __syncthreads();
    for (int i = gb0 + t; i < gb1; i += 512) atomicAdd(&hist[pairs[i] >> 24], 1);
    __syncthreads();
    if (t < NPB) ssum[t] = hist[t];
    __syncthreads();
    for (int off = 1; off < NPB; off <<= 1) {
        int v = 0;
        if (t >= off && t < NPB) v = ssum[t - off];
        __syncthreads();
        if (t < NPB) ssum[t] += v;
        __syncthreads();
    }
    if (t < NPB) {
        int excl = (t == 0) ? 0 : ssum[t - 1];
        cur[t] = excl;
        if (t < nn) {
            csr_off[nb0 + t] = gb0 + excl;
            invd[nb0 + t] = 1.0f / (float)max(hist[t], 1);
        }
    }
    __syncthreads();
    for (int i = gb0 + t; i < gb1; i += 512) {
        unsigned p = pairs[i];
        int ld = p >> 24;
        int pos = atomicAdd(&cur[ld], 1);
        csr_src[gb0 + pos] = (int)(p & 0xFFFFFFu);
    }
}

// ---------------- feature pipeline ----------------

__global__ void pad_x16(const float* __restrict__ x, float* __restrict__ xp, int N) {
    int i = blockIdx.x * blockDim.x + threadIdx.x;
    if (i < N * 16) {
        int n = i >> 4, c = i & 15;
        xp[i] = (c < 13) ? x[n * 13 + c] : 0.f;
    }
}

__global__ __launch_bounds__(512) void sage_layer0(
    const float* __restrict__ x16, const int* __restrict__ off, const int* __restrict__ csr,
    const float* __restrict__ invd, const float* __restrict__ Wl, const float* __restrict__ bl,
    const float* __restrict__ Wr, float* __restrict__ y, int N) {
    __shared__ float wl[16][64];
    __shared__ float wr[16][64];
    __shared__ float bs[64];
    int t = threadIdx.x;
    for (int i = t; i < 16 * 64; i += 512) {
        int k = i >> 6, j = i & 63;
        wl[k][j] = (k < 13) ? Wl[k * 64 + j] : 0.f;
        wr[k][j] = (k < 13) ? Wr[k * 64 + j] : 0.f;
    }
    if (t < 64) bs[t] = bl[t];
    __syncthreads();

    int lane = t & 63, wid = t >> 6;
    int n = blockIdx.x * 8 + wid;
    if (n >= N) return;

    int e0 = off[n], e1 = off[n + 1];
    int g = lane >> 4, c = lane & 15;
    float acc = 0.f;
    int e = e0;
    for (; e + 7 < e1; e += 8) {
        int s0 = csr[e + g];
        int s1 = csr[e + 4 + g];
        acc += x16[s0 * 16 + c] + x16[s1 * 16 + c];
    }
    for (; e + 3 < e1; e += 4) acc += x16[csr[e + g] * 16 + c];
    if (e + g < e1) acc += x16[csr[e + g] * 16 + c];

    acc += __shfl_xor(acc, 16);
    acc += __shfl_xor(acc, 32);
    acc *= invd[n];

    float xv = x16[n * 16 + c];
    float out = bs[lane];
#pragma unroll
    for (int k = 0; k < 16; k++) {
        float a = __shfl(acc, k);
        float b = __shfl(xv, k);
        out += a * wl[k][lane] + b * wr[k][lane];
    }
    y[n * 64 + lane] = fmaxf(out, 0.f);
}

__global__ __launch_bounds__(512) void sage_layer(
    const float* __restrict__ x, const int* __restrict__ off, const int* __restrict__ csr,
    const float* __restrict__ invd, const float* __restrict__ Wl, const float* __restrict__ bl,
    const float* __restrict__ Wr, float* __restrict__ y, int N) {
    __shared__ float wl[64][64];
    __shared__ float wr[64][64];
    __shared__ float bs[64];
    int t = threadIdx.x;
    for (int i = t; i < 64 * 64; i += 512) {
        int k = i >> 6, j = i & 63;
        wl[k][j] = Wl[i];
        wr[k][j] = Wr[i];
    }
    if (t < 64) bs[t] = bl[t];
    __syncthreads();

    int lane = t & 63, wid = t >> 6;
    int n = blockIdx.x * 8 + wid;
    if (n >= N) return;

    float xv = x[n * 64 + lane];
    int e0 = off[n], e1 = off[n + 1];
    float acc = 0.f;
    int e = e0;
    for (; e + 7 < e1; e += 8) {
        int s[8];
#pragma unroll
        for (int j = 0; j < 8; j++) s[j] = csr[e + j];
        float a[8];
#pragma unroll
        for (int j = 0; j < 8; j++) a[j] = x[s[j] * 64 + lane];
#pragma unroll
        for (int j = 0; j < 8; j++) acc += a[j];
    }
    for (; e < e1; e++) acc += x[csr[e] * 64 + lane];
    acc *= invd[n];

    float out = bs[lane];
#pragma unroll
    for (int k = 0; k < 64; k++) {
        float a = __shfl(acc, k);
        float b = __shfl(xv, k);
        out += a * wl[k][lane] + b * wr[k][lane];
    }
    y[n * 64 + lane] = fmaxf(out, 0.f);
}

__global__ __launch_bounds__(512) void proj_last(
    const float* __restrict__ x, const float* __restrict__ Wl, const float* __restrict__ bl,
    const float* __restrict__ Wr, float* __restrict__ s3, float* __restrict__ r3, int N) {
    int t = threadIdx.x, lane = t & 63, wid = t >> 6;
    int n = blockIdx.x * 8 + wid;
    if (n >= N) return;
    float xv = x[n * 64 + lane];
    float p = xv * Wl[lane];
    float q = xv * Wr[lane];
#pragma unroll
    for (int o = 32; o > 0; o >>= 1) {
        p += __shfl_xor(p, o);
        q += __shfl_xor(q, o);
    }
    if (lane == 0) {
        s3[n] = p;
        r3[n] = q + bl[0];
    }
}

__global__ void sage_last_scalar(
    const float* __restrict__ s3, const float* __restrict__ r3, const int* __restrict__ off,
    const int* __restrict__ csr, const float* __restrict__ invd, float* __restrict__ out, int N) {
    int n = blockIdx.x * blockDim.x + threadIdx.x;
    if (n >= N) return;
    int e0 = off[n], e1 = off[n + 1];
    float acc = 0.f;
    int e = e0;
    for (; e + 3 < e1; e += 4) {
        float a0 = s3[csr[e]], a1 = s3[csr[e + 1]], a2 = s3[csr[e + 2]], a3 = s3[csr[e + 3]];
        acc += a0 + a1 + a2 + a3;
    }
    for (; e < e1; e++) acc += s3[csr[e]];
    out[n] = acc * invd[n] + r3[n];
}

// ---------------- launch ----------------

extern "C" void kernel_launch(void* const* d_in, const int* in_sizes, int n_in,
                              void* d_out, int out_size, void* d_ws, size_t ws_size,
                              hipStream_t stream) {
    const float* x0 = (const float*)d_in[0];
    const int* ei = (const int*)d_in[1];
    const float* Wl[4] = {(const float*)d_in[2], (const float*)d_in[5], (const float*)d_in[8],
                          (const float*)d_in[11]};
    const float* bl[4] = {(const float*)d_in[3], (const float*)d_in[6], (const float*)d_in[9],
                          (const float*)d_in[12]};
    const float* Wr[4] = {(const float*)d_in[4], (const float*)d_in[7], (const float*)d_in[10],
                          (const float*)d_in[13]};
    float* out = (float*)d_out;

    const int N = in_sizes[0] / 13;
    const int E = in_sizes[1] / 2;
    const int nbuk = (N + NPB - 1) / NPB;

    char* w = (char*)d_ws;
    auto carve = [&](size_t bytes) {
        void* p = (void*)w;
        w += (bytes + 255) & ~size_t(255);
        return p;
    };
    int* bcnt = (int*)carve((size_t)MAXBUK * 4);
    int* bboff = (int*)carve((size_t)(MAXBUK + 1) * 4);
    int* bcur = (int*)carve((size_t)MAXBUK * 4);
    unsigned int* pairs = (unsigned int*)carve((size_t)E * 4);
    int* csr_off = (int*)carve((size_t)(N + 1) * 4);
    int* csr_src = (int*)carve((size_t)E * 4);
    float* invd = (float*)carve((size_t)N * 4);
    float* x16 = (float*)carve((size_t)N * 16 * 4);
    float* xa = (float*)carve((size_t)N * 64 * 4);
    float* xb = (float*)carve((size_t)N * 64 * 4);
    float* s3 = (float*)carve((size_t)N * 4);
    float* r3 = (float*)carve((size_t)N * 4);

    hipMemsetAsync(bcnt, 0, (size_t)MAXBUK * 4, stream);

    bucket_hist<<<1024, 256, 0, stream>>>(ei, E, bcnt, nbuk);
    bucket_scan<<<1, 512, 0, stream>>>(bcnt, bboff, bcur, nbuk, csr_off, N, E);
    partition<<<(E + A3_TILE - 1) / A3_TILE, 256, 0, stream>>>(ei, E, bcur, pairs);
    build_bucket<<<nbuk, 512, 0, stream>>>(pairs, bboff, csr_off, csr_src, invd, N);

    pad_x16<<<(N * 16 + NT - 1) / NT, NT, 0, stream>>>(x0, x16, N);

    int nblk8 = (N + 7) / 8;
    sage_layer0<<<nblk8, 512, 0, stream>>>(x16, csr_off, csr_src, invd, Wl[0], bl[0], Wr[0], xa, N);
    sage_layer<<<nblk8, 512, 0, stream>>>(xa, csr_off, csr_src, invd, Wl[1], bl[1], Wr[1], xb, N);
    sage_layer<<<nblk8, 512, 0, stream>>>(xb, csr_off, csr_src, invd, Wl[2], bl[2], Wr[2], xa, N);
    proj_last<<<nblk8, 512, 0, stream>>>(xa, Wl[3], bl[3], Wr[3], s3, r3, N);
    sage_last_scalar<<<(N + NT - 1) / NT, NT, 0, stream>>>(s3, r3, csr_off, csr_src, invd, out, N);
}

// Round 4
// 688.691 us; speedup vs baseline: 2.3151x; 1.0376x over previous
//
#include <hip/hip_runtime.h>

#define NT 256
#define NPB 256        // nodes per bucket (dst >> 8)
#define MAXBUK 512     // LDS-side padding for bucket arrays
#define A3_TILE 4096   // edges per partition block (256 thr x 16)

// ---------------- bucketed CSR build ----------------

__global__ __launch_bounds__(256) void bucket_hist(const int* __restrict__ ei, int E,
                                                   int* __restrict__ bcnt, int nbuk) {
    __shared__ int h[MAXBUK];
    int t = threadIdx.x;
    for (int i = t; i < MAXBUK; i += 256) h[i] = 0;
    __syncthreads();
    const int* dsts = ei + E;
    int i0 = blockIdx.x * 256 + t;
    int stride = gridDim.x * 256;
    if ((E & 3) == 0) {
        const int4* d4 = (const int4*)dsts;
        int n4 = E >> 2;
        for (int i = i0; i < n4; i += stride) {
            int4 v = d4[i];
            atomicAdd(&h[v.x >> 8], 1);
            atomicAdd(&h[v.y >> 8], 1);
            atomicAdd(&h[v.z >> 8], 1);
            atomicAdd(&h[v.w >> 8], 1);
        }
    } else {
        for (int e = i0; e < E; e += stride) atomicAdd(&h[dsts[e] >> 8], 1);
    }
    __syncthreads();
    for (int b = t; b < nbuk; b += 256)
        if (h[b]) atomicAdd(&bcnt[b], h[b]);
}

__global__ __launch_bounds__(512) void bucket_scan(const int* __restrict__ bcnt,
                                                   int* __restrict__ bboff, int* __restrict__ bcur,
                                                   int nbuk, int* __restrict__ csr_off, int N,
                                                   int E) {
    __shared__ int s[512];
    int t = threadIdx.x;
    s[t] = (t < nbuk) ? bcnt[t] : 0;
    __syncthreads();
    for (int off = 1; off < 512; off <<= 1) {
        int v = 0;
        if (t >= off) v = s[t - off];
        __syncthreads();
        s[t] += v;
        __syncthreads();
    }
    int excl = (t == 0) ? 0 : s[t - 1];
    if (t <= nbuk) {
        bboff[t] = excl;
        if (t < nbuk) bcur[t] = excl;
    }
    if (t == 0) csr_off[N] = E;
}

__global__ __launch_bounds__(256) void partition(const int* __restrict__ ei, int E,
                                                 int* __restrict__ bcur,
                                                 unsigned int* __restrict__ pairs) {
    __shared__ int h[MAXBUK];
    __shared__ int base[MAXBUK];
    int t = threadIdx.x;
    for (int i = t; i < MAXBUK; i += 256) h[i] = 0;
    __syncthreads();
    int e0 = blockIdx.x * A3_TILE + t * 16;  // 16 contiguous edges per thread
    int src[16], dst[16];
    if (((E & 3) == 0) && (e0 + 15 < E)) {
        const int4* p4s = (const int4*)(ei + e0);
        const int4* p4d = (const int4*)(ei + E + e0);
#pragma unroll
        for (int j4 = 0; j4 < 4; j4++) {
            int4 s4 = p4s[j4];
            int4 d4 = p4d[j4];
            src[j4 * 4 + 0] = s4.x; dst[j4 * 4 + 0] = d4.x;
            src[j4 * 4 + 1] = s4.y; dst[j4 * 4 + 1] = d4.y;
            src[j4 * 4 + 2] = s4.z; dst[j4 * 4 + 2] = d4.z;
            src[j4 * 4 + 3] = s4.w; dst[j4 * 4 + 3] = d4.w;
        }
    } else {
#pragma unroll
        for (int j = 0; j < 16; j++) {
            int e = e0 + j;
            if (e < E) {
                src[j] = ei[e];
                dst[j] = ei[E + e];
            } else {
                dst[j] = -1;
            }
        }
    }
#pragma unroll
    for (int j = 0; j < 16; j++)
        if (dst[j] >= 0) atomicAdd(&h[dst[j] >> 8], 1);
    __syncthreads();
    for (int b = t; b < MAXBUK; b += 256) {
        int c = h[b];
        base[b] = c ? atomicAdd(&bcur[b], c) : 0;
        h[b] = 0;  // becomes local cursor
    }
    __syncthreads();
#pragma unroll
    for (int j = 0; j < 16; j++) {
        if (dst[j] >= 0) {
            int bkt = dst[j] >> 8;
            int r = atomicAdd(&h[bkt], 1);
            pairs[base[bkt] + r] = ((unsigned)(dst[j] & (NPB - 1)) << 24) | (unsigned)src[j];
        }
    }
}

__global__ __launch_bounds__(512) void build_bucket(const unsigned int* __restrict__ pairs,
                                                    const int* __restrict__ bboff,
                                                    int* __restrict__ csr_off,
                                                    int* __restrict__ csr_src,
                                                    float* __restrict__ invd, int N) {
    __shared__ int hist[NPB];
    __shared__ int ssum[NPB];
    __shared__ int cur[NPB];
    int b = blockIdx.x, t = threadIdx.x;
    int gb0 = bboff[b], gb1 = bboff[b + 1];
    int nb0 = b << 8;
    int nn = min(NPB, N - nb0);
    for (int i = t; i < NPB; i += 512) hist[i] = 0;
    __syncthreads();
    for (int i = gb0 + t; i < gb1; i += 512) atomicAdd(&hist[pairs[i] >> 24], 1);
    __syncthreads();
    if (t < NPB) ssum[t] = hist[t];
    __syncthreads();
    for (int off = 1; off < NPB; off <<= 1) {
        int v = 0;
        if (t >= off && t < NPB) v = ssum[t - off];
        __syncthreads();
        if (t < NPB) ssum[t] += v;
        __syncthreads();
    }
    if (t < NPB) {
        int excl = (t == 0) ? 0 : ssum[t - 1];
        cur[t] = excl;
        if (t < nn) {
            csr_off[nb0 + t] = gb0 + excl;
            invd[nb0 + t] = 1.0f / (float)max(hist[t], 1);
        }
    }
    __syncthreads();
    for (int i = gb0 + t; i < gb1; i += 512) {
        unsigned p = pairs[i];
        int ld = p >> 24;
        int pos = atomicAdd(&cur[ld], 1);
        csr_src[gb0 + pos] = (int)(p & 0xFFFFFFu);
    }
}

// ---------------- feature pipeline ----------------

__global__ void pad_x16(const float* __restrict__ x, float* __restrict__ xp, int N) {
    int i = blockIdx.x * blockDim.x + threadIdx.x;
    if (i < N * 16) {
        int n = i >> 4, c = i & 15;
        xp[i] = (c < 13) ? x[n * 13 + c] : 0.f;
    }
}

// layer 0: float4 gather in 16-ch space -> 16 edges per wave load instruction
__global__ __launch_bounds__(512) void sage_layer0(
    const float* __restrict__ x16, const int* __restrict__ off, const int* __restrict__ csr,
    const float* __restrict__ invd, const float* __restrict__ Wl, const float* __restrict__ bl,
    const float* __restrict__ Wr, float* __restrict__ y, int N) {
    __shared__ float wl[16][64];
    __shared__ float wr[16][64];
    __shared__ float bs[64];
    int t = threadIdx.x;
    for (int i = t; i < 16 * 64; i += 512) {
        int k = i >> 6, j = i & 63;
        wl[k][j] = (k < 13) ? Wl[k * 64 + j] : 0.f;
        wr[k][j] = (k < 13) ? Wr[k * 64 + j] : 0.f;
    }
    if (t < 64) bs[t] = bl[t];
    __syncthreads();

    int lane = t & 63, wid = t >> 6;
    int n = blockIdx.x * 8 + wid;
    if (n >= N) return;

    int g = lane >> 2;         // edge subgroup 0..15
    int c4 = (lane & 3) * 4;   // channel base (components c4..c4+3)
    float4 xv = *(const float4*)&x16[n * 16 + c4];

    int e0 = off[n], e1 = off[n + 1];
    float ax = 0.f, ay = 0.f, az = 0.f, aw = 0.f;
    int e = e0;
    for (; e + 15 < e1; e += 16) {
        int s0 = csr[e + g];
        float4 a = *(const float4*)&x16[s0 * 16 + c4];
        ax += a.x; ay += a.y; az += a.z; aw += a.w;
    }
    if (e + g < e1) {
        float4 a = *(const float4*)&x16[csr[e + g] * 16 + c4];
        ax += a.x; ay += a.y; az += a.z; aw += a.w;
    }
    // reduce across the 16 groups (xor bits 2..5)
#pragma unroll
    for (int o = 4; o <= 32; o <<= 1) {
        ax += __shfl_xor(ax, o);
        ay += __shfl_xor(ay, o);
        az += __shfl_xor(az, o);
        aw += __shfl_xor(aw, o);
    }
    float s = invd[n];
    ax *= s; ay *= s; az *= s; aw *= s;

    float out = bs[lane];
#pragma unroll
    for (int q = 0; q < 4; q++) {
        float a0 = __shfl(ax, q), a1 = __shfl(ay, q), a2 = __shfl(az, q), a3 = __shfl(aw, q);
        float b0 = __shfl(xv.x, q), b1 = __shfl(xv.y, q), b2 = __shfl(xv.z, q), b3 = __shfl(xv.w, q);
        out += a0 * wl[4 * q + 0][lane] + b0 * wr[4 * q + 0][lane];
        out += a1 * wl[4 * q + 1][lane] + b1 * wr[4 * q + 1][lane];
        out += a2 * wl[4 * q + 2][lane] + b2 * wr[4 * q + 2][lane];
        out += a3 * wl[4 * q + 3][lane] + b3 * wr[4 * q + 3][lane];
    }
    y[n * 64 + lane] = fmaxf(out, 0.f);
}

// middle layers: float4 gather -> 4 edges per wave load instruction (8 with unroll)
__global__ __launch_bounds__(512) void sage_layer(
    const float* __restrict__ x, const int* __restrict__ off, const int* __restrict__ csr,
    const float* __restrict__ invd, const float* __restrict__ Wl, const float* __restrict__ bl,
    const float* __restrict__ Wr, float* __restrict__ y, int N) {
    __shared__ float wl[64][64];
    __shared__ float wr[64][64];
    __shared__ float bs[64];
    int t = threadIdx.x;
    for (int i = t; i < 64 * 64; i += 512) {
        int k = i >> 6, j = i & 63;
        wl[k][j] = Wl[i];
        wr[k][j] = Wr[i];
    }
    if (t < 64) bs[t] = bl[t];
    __syncthreads();

    int lane = t & 63, wid = t >> 6;
    int n = blockIdx.x * 8 + wid;
    if (n >= N) return;

    int g = lane >> 4;          // edge subgroup 0..3
    int c4 = (lane & 15) * 4;   // channel base
    float4 xv = *(const float4*)&x[n * 64 + c4];

    int e0 = off[n], e1 = off[n + 1];
    float ax = 0.f, ay = 0.f, az = 0.f, aw = 0.f;
    int e = e0;
    for (; e + 7 < e1; e += 8) {
        int s0 = csr[e + g];
        int s1 = csr[e + 4 + g];
        float4 a0 = *(const float4*)&x[s0 * 64 + c4];
        float4 a1 = *(const float4*)&x[s1 * 64 + c4];
        ax += a0.x + a1.x;
        ay += a0.y + a1.y;
        az += a0.z + a1.z;
        aw += a0.w + a1.w;
    }
    if (e + 3 < e1) {
        float4 a = *(const float4*)&x[csr[e + g] * 64 + c4];
        ax += a.x; ay += a.y; az += a.z; aw += a.w;
        e += 4;
    }
    if (e + g < e1) {
        float4 a = *(const float4*)&x[csr[e + g] * 64 + c4];
        ax += a.x; ay += a.y; az += a.z; aw += a.w;
    }
    // reduce across the 4 groups
#pragma unroll
    for (int o = 16; o <= 32; o <<= 1) {
        ax += __shfl_xor(ax, o);
        ay += __shfl_xor(ay, o);
        az += __shfl_xor(az, o);
        aw += __shfl_xor(aw, o);
    }
    float s = invd[n];
    ax *= s; ay *= s; az *= s; aw *= s;

    float out = bs[lane];
#pragma unroll
    for (int q = 0; q < 16; q++) {
        float a0 = __shfl(ax, q), a1 = __shfl(ay, q), a2 = __shfl(az, q), a3 = __shfl(aw, q);
        float b0 = __shfl(xv.x, q), b1 = __shfl(xv.y, q), b2 = __shfl(xv.z, q), b3 = __shfl(xv.w, q);
        out += a0 * wl[4 * q + 0][lane] + b0 * wr[4 * q + 0][lane];
        out += a1 * wl[4 * q + 1][lane] + b1 * wr[4 * q + 1][lane];
        out += a2 * wl[4 * q + 2][lane] + b2 * wr[4 * q + 2][lane];
        out += a3 * wl[4 * q + 3][lane] + b3 * wr[4 * q + 3][lane];
    }
    y[n * 64 + lane] = fmaxf(out, 0.f);
}

__global__ __launch_bounds__(512) void proj_last(
    const float* __restrict__ x, const float* __restrict__ Wl, const float* __restrict__ bl,
    const float* __restrict__ Wr, float* __restrict__ s3, float* __restrict__ r3, int N) {
    int t = threadIdx.x, lane = t & 63, wid = t >> 6;
    int n = blockIdx.x * 8 + wid;
    if (n >= N) return;
    float xv = x[n * 64 + lane];
    float p = xv * Wl[lane];
    float q = xv * Wr[lane];
#pragma unroll
    for (int o = 32; o > 0; o >>= 1) {
        p += __shfl_xor(p, o);
        q += __shfl_xor(q, o);
    }
    if (lane == 0) {
        s3[n] = p;
        r3[n] = q + bl[0];
    }
}

__global__ void sage_last_scalar(
    const float* __restrict__ s3, const float* __restrict__ r3, const int* __restrict__ off,
    const int* __restrict__ csr, const float* __restrict__ invd, float* __restrict__ out, int N) {
    int n = blockIdx.x * blockDim.x + threadIdx.x;
    if (n >= N) return;
    int e0 = off[n], e1 = off[n + 1];
    float acc = 0.f;
    int e = e0;
    for (; e + 3 < e1; e += 4) {
        float a0 = s3[csr[e]], a1 = s3[csr[e + 1]], a2 = s3[csr[e + 2]], a3 = s3[csr[e + 3]];
        acc += a0 + a1 + a2 + a3;
    }
    for (; e < e1; e++) acc += s3[csr[e]];
    out[n] = acc * invd[n] + r3[n];
}

// ---------------- launch ----------------

extern "C" void kernel_launch(void* const* d_in, const int* in_sizes, int n_in,
                              void* d_out, int out_size, void* d_ws, size_t ws_size,
                              hipStream_t stream) {
    const float* x0 = (const float*)d_in[0];
    const int* ei = (const int*)d_in[1];
    const float* Wl[4] = {(const float*)d_in[2], (const float*)d_in[5], (const float*)d_in[8],
                          (const float*)d_in[11]};
    const float* bl[4] = {(const float*)d_in[3], (const float*)d_in[6], (const float*)d_in[9],
                          (const float*)d_in[12]};
    const float* Wr[4] = {(const float*)d_in[4], (const float*)d_in[7], (const float*)d_in[10],
                          (const float*)d_in[13]};
    float* out = (float*)d_out;

    const int N = in_sizes[0] / 13;
    const int E = in_sizes[1] / 2;
    const int nbuk = (N + NPB - 1) / NPB;

    char* w = (char*)d_ws;
    auto carve = [&](size_t bytes) {
        void* p = (void*)w;
        w += (bytes + 255) & ~size_t(255);
        return p;
    };
    int* bcnt = (int*)carve((size_t)MAXBUK * 4);
    int* bboff = (int*)carve((size_t)(MAXBUK + 1) * 4);
    int* bcur = (int*)carve((size_t)MAXBUK * 4);
    unsigned int* pairs = (unsigned int*)carve((size_t)E * 4);
    int* csr_off = (int*)carve((size_t)(N + 1) * 4);
    int* csr_src = (int*)carve((size_t)E * 4);
    float* invd = (float*)carve((size_t)N * 4);
    float* x16 = (float*)carve((size_t)N * 16 * 4);
    float* xa = (float*)carve((size_t)N * 64 * 4);
    float* xb = (float*)carve((size_t)N * 64 * 4);
    float* s3 = (float*)carve((size_t)N * 4);
    float* r3 = (float*)carve((size_t)N * 4);

    hipMemsetAsync(bcnt, 0, (size_t)MAXBUK * 4, stream);

    bucket_hist<<<1024, 256, 0, stream>>>(ei, E, bcnt, nbuk);
    bucket_scan<<<1, 512, 0, stream>>>(bcnt, bboff, bcur, nbuk, csr_off, N, E);
    partition<<<(E + A3_TILE - 1) / A3_TILE, 256, 0, stream>>>(ei, E, bcur, pairs);
    build_bucket<<<nbuk, 512, 0, stream>>>(pairs, bboff, csr_off, csr_src, invd, N);

    pad_x16<<<(N * 16 + NT - 1) / NT, NT, 0, stream>>>(x0, x16, N);

    int nblk8 = (N + 7) / 8;
    sage_layer0<<<nblk8, 512, 0, stream>>>(x16, csr_off, csr_src, invd, Wl[0], bl[0], Wr[0], xa, N);
    sage_layer<<<nblk8, 512, 0, stream>>>(xa, csr_off, csr_src, invd, Wl[1], bl[1], Wr[1], xb, N);
    sage_layer<<<nblk8, 512, 0, stream>>>(xb, csr_off, csr_src, invd, Wl[2], bl[2], Wr[2], xa, N);
    proj_last<<<nblk8, 512, 0, stream>>>(xa, Wl[3], bl[3], Wr[3], s3, r3, N);
    sage_last_scalar<<<(N + NT - 1) / NT, NT, 0, stream>>>(s3, r3, csr_off, csr_src, invd, out, N);
}

// Round 5
// 667.297 us; speedup vs baseline: 2.3893x; 1.0321x over previous
//
#include <hip/hip_runtime.h>
#include <hip/hip_fp16.h>

#define NT 256
#define NPB 256        // nodes per bucket (dst >> 8)
#define MAXBUK 512     // LDS-side padding for bucket arrays
#define A3_TILE 4096   // edges per partition block (256 thr x 16)

// ---------------- bucketed CSR build ----------------

__global__ __launch_bounds__(256) void bucket_hist(const int* __restrict__ ei, int E,
                                                   int* __restrict__ bcnt, int nbuk) {
    __shared__ int h[MAXBUK];
    int t = threadIdx.x;
    for (int i = t; i < MAXBUK; i += 256) h[i] = 0;
    __syncthreads();
    const int* dsts = ei + E;
    int i0 = blockIdx.x * 256 + t;
    int stride = gridDim.x * 256;
    if ((E & 3) == 0) {
        const int4* d4 = (const int4*)dsts;
        int n4 = E >> 2;
        for (int i = i0; i < n4; i += stride) {
            int4 v = d4[i];
            atomicAdd(&h[v.x >> 8], 1);
            atomicAdd(&h[v.y >> 8], 1);
            atomicAdd(&h[v.z >> 8], 1);
            atomicAdd(&h[v.w >> 8], 1);
        }
    } else {
        for (int e = i0; e < E; e += stride) atomicAdd(&h[dsts[e] >> 8], 1);
    }
    __syncthreads();
    for (int b = t; b < nbuk; b += 256)
        if (h[b]) atomicAdd(&bcnt[b], h[b]);
}

__global__ __launch_bounds__(512) void bucket_scan(const int* __restrict__ bcnt,
                                                   int* __restrict__ bboff, int* __restrict__ bcur,
                                                   int nbuk, int* __restrict__ csr_off, int N,
                                                   int E) {
    __shared__ int s[512];
    int t = threadIdx.x;
    s[t] = (t < nbuk) ? bcnt[t] : 0;
    __syncthreads();
    for (int off = 1; off < 512; off <<= 1) {
        int v = 0;
        if (t >= off) v = s[t - off];
        __syncthreads();
        s[t] += v;
        __syncthreads();
    }
    int excl = (t == 0) ? 0 : s[t - 1];
    if (t <= nbuk) {
        bboff[t] = excl;
        if (t < nbuk) bcur[t] = excl;
    }
    if (t == 0) csr_off[N] = E;
}

__global__ __launch_bounds__(256) void partition(const int* __restrict__ ei, int E,
                                                 int* __restrict__ bcur,
                                                 unsigned int* __restrict__ pairs) {
    __shared__ int h[MAXBUK];
    __shared__ int base[MAXBUK];
    int t = threadIdx.x;
    for (int i = t; i < MAXBUK; i += 256) h[i] = 0;
    __syncthreads();
    int e0 = blockIdx.x * A3_TILE + t * 16;
    int src[16], dst[16];
    if (((E & 3) == 0) && (e0 + 15 < E)) {
        const int4* p4s = (const int4*)(ei + e0);
        const int4* p4d = (const int4*)(ei + E + e0);
#pragma unroll
        for (int j4 = 0; j4 < 4; j4++) {
            int4 s4 = p4s[j4];
            int4 d4 = p4d[j4];
            src[j4 * 4 + 0] = s4.x; dst[j4 * 4 + 0] = d4.x;
            src[j4 * 4 + 1] = s4.y; dst[j4 * 4 + 1] = d4.y;
            src[j4 * 4 + 2] = s4.z; dst[j4 * 4 + 2] = d4.z;
            src[j4 * 4 + 3] = s4.w; dst[j4 * 4 + 3] = d4.w;
        }
    } else {
#pragma unroll
        for (int j = 0; j < 16; j++) {
            int e = e0 + j;
            if (e < E) {
                src[j] = ei[e];
                dst[j] = ei[E + e];
            } else {
                dst[j] = -1;
            }
        }
    }
#pragma unroll
    for (int j = 0; j < 16; j++)
        if (dst[j] >= 0) atomicAdd(&h[dst[j] >> 8], 1);
    __syncthreads();
    for (int b = t; b < MAXBUK; b += 256) {
        int c = h[b];
        base[b] = c ? atomicAdd(&bcur[b], c) : 0;
        h[b] = 0;
    }
    __syncthreads();
#pragma unroll
    for (int j = 0; j < 16; j++) {
        if (dst[j] >= 0) {
            int bkt = dst[j] >> 8;
            int r = atomicAdd(&h[bkt], 1);
            pairs[base[bkt] + r] = ((unsigned)(dst[j] & (NPB - 1)) << 24) | (unsigned)src[j];
        }
    }
}

__global__ __launch_bounds__(512) void build_bucket(const unsigned int* __restrict__ pairs,
                                                    const int* __restrict__ bboff,
                                                    int* __restrict__ csr_off,
                                                    int* __restrict__ csr_src,
                                                    float* __restrict__ invd, int N) {
    __shared__ int hist[NPB];
    __shared__ int ssum[NPB];
    __shared__ int cur[NPB];
    int b = blockIdx.x, t = threadIdx.x;
    int gb0 = bboff[b], gb1 = bboff[b + 1];
    int nb0 = b << 8;
    int nn = min(NPB, N - nb0);
    for (int i = t; i < NPB; i += 512) hist[i] = 0;
    __syncthreads();
    for (int i = gb0 + t; i < gb1; i += 512) atomicAdd(&hist[pairs[i] >> 24], 1);
    __syncthreads();
    if (t < NPB) ssum[t] = hist[t];
    __syncthreads();
    for (int off = 1; off < NPB; off <<= 1) {
        int v = 0;
        if (t >= off && t < NPB) v = ssum[t - off];
        __syncthreads();
        if (t < NPB) ssum[t] += v;
        __syncthreads();
    }
    if (t < NPB) {
        int excl = (t == 0) ? 0 : ssum[t - 1];
        cur[t] = excl;
        if (t < nn) {
            csr_off[nb0 + t] = gb0 + excl;
            invd[nb0 + t] = 1.0f / (float)max(hist[t], 1);
        }
    }
    __syncthreads();
    for (int i = gb0 + t; i < gb1; i += 512) {
        unsigned p = pairs[i];
        int ld = p >> 24;
        int pos = atomicAdd(&cur[ld], 1);
        csr_src[gb0 + pos] = (int)(p & 0xFFFFFFu);
    }
}

// ---------------- feature pipeline ----------------

__device__ inline void acc8(float* acc, uint4 hv) {
    const __half2* hp = reinterpret_cast<const __half2*>(&hv);
#pragma unroll
    for (int j = 0; j < 4; j++) {
        float2 f = __half22float2(hp[j]);
        acc[2 * j] += f.x;
        acc[2 * j + 1] += f.y;
    }
}

// pack x [N,13] -> f32 [N,16] + fp16 [N,16]
__global__ void pad_x16(const float* __restrict__ x, float* __restrict__ xf,
                        __half* __restrict__ xh, int N) {
    int i = blockIdx.x * blockDim.x + threadIdx.x;
    if (i < N * 16) {
        int n = i >> 4, c = i & 15;
        float v = (c < 13) ? x[n * 13 + c] : 0.f;
        xf[i] = v;
        xh[i] = __float2half(v);
    }
}

// layer 0: fp16 gather in 16-ch space -> 32 edges per wave load instruction
__global__ __launch_bounds__(512) void sage_layer0(
    const float* __restrict__ x16f, const __half* __restrict__ x16h,
    const int* __restrict__ off, const int* __restrict__ csr, const float* __restrict__ invd,
    const float* __restrict__ Wl, const float* __restrict__ bl, const float* __restrict__ Wr,
    float* __restrict__ y, __half* __restrict__ yh, int N) {
    __shared__ float wl[16][64];
    __shared__ float wr[16][64];
    __shared__ float bs[64];
    int t = threadIdx.x;
    for (int i = t; i < 16 * 64; i += 512) {
        int k = i >> 6, j = i & 63;
        wl[k][j] = (k < 13) ? Wl[k * 64 + j] : 0.f;
        wr[k][j] = (k < 13) ? Wr[k * 64 + j] : 0.f;
    }
    if (t < 64) bs[t] = bl[t];
    __syncthreads();

    int lane = t & 63, wid = t >> 6;
    int n = blockIdx.x * 8 + wid;
    if (n >= N) return;

    int g = lane >> 1;          // edge subgroup 0..31
    int c8 = (lane & 1) * 8;    // channel octet base
    float s = invd[n];
    int e0 = off[n], e1 = off[n + 1];

    float acc[8] = {0, 0, 0, 0, 0, 0, 0, 0};
    int e = e0;
    for (; e + 31 < e1; e += 32) {
        int s0 = csr[e + g];
        uint4 h = *(const uint4*)(x16h + (size_t)s0 * 16 + c8);
        acc8(acc, h);
    }
    if (e + g < e1) {
        int s0 = csr[e + g];
        uint4 h = *(const uint4*)(x16h + (size_t)s0 * 16 + c8);
        acc8(acc, h);
    }
#pragma unroll
    for (int o = 2; o <= 32; o <<= 1) {
#pragma unroll
        for (int j = 0; j < 8; j++) acc[j] += __shfl_xor(acc[j], o);
    }
#pragma unroll
    for (int j = 0; j < 8; j++) acc[j] *= s;

    float4 xv0 = *(const float4*)(x16f + (size_t)n * 16 + c8);
    float4 xv1 = *(const float4*)(x16f + (size_t)n * 16 + c8 + 4);
    float xvf[8] = {xv0.x, xv0.y, xv0.z, xv0.w, xv1.x, xv1.y, xv1.z, xv1.w};

    float out = bs[lane];
#pragma unroll
    for (int j = 0; j < 8; j++) {
#pragma unroll
        for (int l = 0; l < 2; l++) {
            int k = l * 8 + j;
            float a = __shfl(acc[j], l);
            float b = __shfl(xvf[j], l);
            out += a * wl[k][lane] + b * wr[k][lane];
        }
    }
    out = fmaxf(out, 0.f);
    y[(size_t)n * 64 + lane] = out;
    yh[(size_t)n * 64 + lane] = __float2half(out);
}

// middle layers: fp16 gather (8 edges per wave load), f32 root, dual write
__global__ __launch_bounds__(512) void sage_layer(
    const float* __restrict__ x, const __half* __restrict__ xh,
    const int* __restrict__ off, const int* __restrict__ csr, const float* __restrict__ invd,
    const float* __restrict__ Wl, const float* __restrict__ bl, const float* __restrict__ Wr,
    float* __restrict__ y, __half* __restrict__ yh, int N) {
    __shared__ float wl[64][64];
    __shared__ float wr[64][64];
    __shared__ float bs[64];
    int t = threadIdx.x;
    for (int i = t; i < 64 * 64; i += 512) {
        int k = i >> 6, j = i & 63;
        wl[k][j] = Wl[i];
        wr[k][j] = Wr[i];
    }
    if (t < 64) bs[t] = bl[t];
    __syncthreads();

    int lane = t & 63, wid = t >> 6;
    int n = blockIdx.x * 8 + wid;
    if (n >= N) return;

    int g = lane >> 3;          // edge subgroup 0..7
    int c8 = (lane & 7) * 8;    // channel octet base
    float s = invd[n];
    int e0 = off[n], e1 = off[n + 1];

    float acc[8] = {0, 0, 0, 0, 0, 0, 0, 0};
    int e = e0;
    for (; e + 15 < e1; e += 16) {
        int s0 = csr[e + g];
        int s1 = csr[e + 8 + g];
        uint4 h0 = *(const uint4*)(xh + (size_t)s0 * 64 + c8);
        uint4 h1 = *(const uint4*)(xh + (size_t)s1 * 64 + c8);
        acc8(acc, h0);
        acc8(acc, h1);
    }
    if (e + 7 < e1) {
        int s0 = csr[e + g];
        uint4 h0 = *(const uint4*)(xh + (size_t)s0 * 64 + c8);
        acc8(acc, h0);
        e += 8;
    }
    if (e + g < e1) {
        int s0 = csr[e + g];
        uint4 h0 = *(const uint4*)(xh + (size_t)s0 * 64 + c8);
        acc8(acc, h0);
    }
#pragma unroll
    for (int o = 8; o <= 32; o <<= 1) {
#pragma unroll
        for (int j = 0; j < 8; j++) acc[j] += __shfl_xor(acc[j], o);
    }
#pragma unroll
    for (int j = 0; j < 8; j++) acc[j] *= s;

    float4 xv0 = *(const float4*)(x + (size_t)n * 64 + c8);
    float4 xv1 = *(const float4*)(x + (size_t)n * 64 + c8 + 4);
    float xvf[8] = {xv0.x, xv0.y, xv0.z, xv0.w, xv1.x, xv1.y, xv1.z, xv1.w};

    float out = bs[lane];
#pragma unroll
    for (int j = 0; j < 8; j++) {
#pragma unroll
        for (int l = 0; l < 8; l++) {
            int k = l * 8 + j;
            float a = __shfl(acc[j], l);
            float b = __shfl(xvf[j], l);
            out += a * wl[k][lane] + b * wr[k][lane];
        }
    }
    out = fmaxf(out, 0.f);
    y[(size_t)n * 64 + lane] = out;
    yh[(size_t)n * 64 + lane] = __float2half(out);
}

__global__ __launch_bounds__(512) void proj_last(
    const float* __restrict__ x, const float* __restrict__ Wl, const float* __restrict__ bl,
    const float* __restrict__ Wr, float* __restrict__ s3, float* __restrict__ r3, int N) {
    int t = threadIdx.x, lane = t & 63, wid = t >> 6;
    int n = blockIdx.x * 8 + wid;
    if (n >= N) return;
    float xv = x[(size_t)n * 64 + lane];
    float p = xv * Wl[lane];
    float q = xv * Wr[lane];
#pragma unroll
    for (int o = 32; o > 0; o >>= 1) {
        p += __shfl_xor(p, o);
        q += __shfl_xor(q, o);
    }
    if (lane == 0) {
        s3[n] = p;
        r3[n] = q + bl[0];
    }
}

__global__ void sage_last_scalar(
    const float* __restrict__ s3, const float* __restrict__ r3, const int* __restrict__ off,
    const int* __restrict__ csr, const float* __restrict__ invd, float* __restrict__ out, int N) {
    int n = blockIdx.x * blockDim.x + threadIdx.x;
    if (n >= N) return;
    int e0 = off[n], e1 = off[n + 1];
    float acc = 0.f;
    int e = e0;
    for (; e + 3 < e1; e += 4) {
        float a0 = s3[csr[e]], a1 = s3[csr[e + 1]], a2 = s3[csr[e + 2]], a3 = s3[csr[e + 3]];
        acc += a0 + a1 + a2 + a3;
    }
    for (; e < e1; e++) acc += s3[csr[e]];
    out[n] = acc * invd[n] + r3[n];
}

// ---------------- launch ----------------

extern "C" void kernel_launch(void* const* d_in, const int* in_sizes, int n_in,
                              void* d_out, int out_size, void* d_ws, size_t ws_size,
                              hipStream_t stream) {
    const float* x0 = (const float*)d_in[0];
    const int* ei = (const int*)d_in[1];
    const float* Wl[4] = {(const float*)d_in[2], (const float*)d_in[5], (const float*)d_in[8],
                          (const float*)d_in[11]};
    const float* bl[4] = {(const float*)d_in[3], (const float*)d_in[6], (const float*)d_in[9],
                          (const float*)d_in[12]};
    const float* Wr[4] = {(const float*)d_in[4], (const float*)d_in[7], (const float*)d_in[10],
                          (const float*)d_in[13]};
    float* out = (float*)d_out;

    const int N = in_sizes[0] / 13;
    const int E = in_sizes[1] / 2;
    const int nbuk = (N + NPB - 1) / NPB;

    char* w = (char*)d_ws;
    auto carve = [&](size_t bytes) {
        void* p = (void*)w;
        w += (bytes + 255) & ~size_t(255);
        return p;
    };
    int* bcnt = (int*)carve((size_t)MAXBUK * 4);
    int* bboff = (int*)carve((size_t)(MAXBUK + 1) * 4);
    int* bcur = (int*)carve((size_t)MAXBUK * 4);
    unsigned int* pairs = (unsigned int*)carve((size_t)E * 4);  // reused as xbh after build
    int* csr_off = (int*)carve((size_t)(N + 1) * 4);
    int* csr_src = (int*)carve((size_t)E * 4);
    float* invd = (float*)carve((size_t)N * 4);
    float* xa = (float*)carve((size_t)N * 64 * 4);
    __half* xah = (__half*)carve((size_t)N * 64 * 2);
    float* xb = (float*)carve((size_t)N * 64 * 4);  // head doubles as x16f/x16h before L1
    float* s3 = (float*)carve((size_t)N * 4);
    float* r3 = (float*)carve((size_t)N * 4);

    // overlays (regions dead before their second use)
    __half* xbh = (__half*)pairs;                       // pairs dead after build_bucket
    float* x16f = xb;                                   // [N,16] f32 = 6.4 MB
    __half* x16h = (__half*)(xb + (size_t)N * 16);      // [N,16] fp16 = 3.2 MB (within xb's 25.6 MB)

    hipMemsetAsync(bcnt, 0, (size_t)MAXBUK * 4, stream);

    bucket_hist<<<1024, 256, 0, stream>>>(ei, E, bcnt, nbuk);
    bucket_scan<<<1, 512, 0, stream>>>(bcnt, bboff, bcur, nbuk, csr_off, N, E);
    partition<<<(E + A3_TILE - 1) / A3_TILE, 256, 0, stream>>>(ei, E, bcur, pairs);
    build_bucket<<<nbuk, 512, 0, stream>>>(pairs, bboff, csr_off, csr_src, invd, N);

    pad_x16<<<(N * 16 + NT - 1) / NT, NT, 0, stream>>>(x0, x16f, x16h, N);

    int nblk8 = (N + 7) / 8;
    sage_layer0<<<nblk8, 512, 0, stream>>>(x16f, x16h, csr_off, csr_src, invd,
                                           Wl[0], bl[0], Wr[0], xa, xah, N);
    sage_layer<<<nblk8, 512, 0, stream>>>(xa, xah, csr_off, csr_src, invd,
                                          Wl[1], bl[1], Wr[1], xb, xbh, N);
    sage_layer<<<nblk8, 512, 0, stream>>>(xb, xbh, csr_off, csr_src, invd,
                                          Wl[2], bl[2], Wr[2], xa, xah, N);
    proj_last<<<nblk8, 512, 0, stream>>>(xa, Wl[3], bl[3], Wr[3], s3, r3, N);
    sage_last_scalar<<<(N + NT - 1) / NT, NT, 0, stream>>>(s3, r3, csr_off, csr_src, invd, out, N);
}

// Round 6
// 345.862 us; speedup vs baseline: 4.6098x; 1.9294x over previous
//
#include <hip/hip_runtime.h>
#include <hip/hip_fp16.h>

#define NT 256
#define NPB 256        // nodes per bucket (dst >> 8)
#define MAXBUK 512
#define A3_TILE 4096

typedef _Float16 half8 __attribute__((ext_vector_type(8)));
typedef float floatx4 __attribute__((ext_vector_type(4)));

// ---------------- bucketed CSR build ----------------

__global__ __launch_bounds__(256) void bucket_hist(const int* __restrict__ ei, int E,
                                                   int* __restrict__ bcnt, int nbuk) {
    __shared__ int h[MAXBUK];
    int t = threadIdx.x;
    for (int i = t; i < MAXBUK; i += 256) h[i] = 0;
    __syncthreads();
    const int* dsts = ei + E;
    int i0 = blockIdx.x * 256 + t;
    int stride = gridDim.x * 256;
    if ((E & 3) == 0) {
        const int4* d4 = (const int4*)dsts;
        int n4 = E >> 2;
        for (int i = i0; i < n4; i += stride) {
            int4 v = d4[i];
            atomicAdd(&h[v.x >> 8], 1);
            atomicAdd(&h[v.y >> 8], 1);
            atomicAdd(&h[v.z >> 8], 1);
            atomicAdd(&h[v.w >> 8], 1);
        }
    } else {
        for (int e = i0; e < E; e += stride) atomicAdd(&h[dsts[e] >> 8], 1);
    }
    __syncthreads();
    for (int b = t; b < nbuk; b += 256)
        if (h[b]) atomicAdd(&bcnt[b], h[b]);
}

__global__ __launch_bounds__(512) void bucket_scan(const int* __restrict__ bcnt,
                                                   int* __restrict__ bboff, int* __restrict__ bcur,
                                                   int nbuk, int* __restrict__ csr_off, int N,
                                                   int E) {
    __shared__ int s[512];
    int t = threadIdx.x;
    s[t] = (t < nbuk) ? bcnt[t] : 0;
    __syncthreads();
    for (int off = 1; off < 512; off <<= 1) {
        int v = 0;
        if (t >= off) v = s[t - off];
        __syncthreads();
        s[t] += v;
        __syncthreads();
    }
    int excl = (t == 0) ? 0 : s[t - 1];
    if (t <= nbuk) {
        bboff[t] = excl;
        if (t < nbuk) bcur[t] = excl;
    }
    if (t == 0) csr_off[N] = E;
}

__global__ __launch_bounds__(256) void partition(const int* __restrict__ ei, int E,
                                                 int* __restrict__ bcur,
                                                 unsigned int* __restrict__ pairs) {
    __shared__ int h[MAXBUK];
    __shared__ int base[MAXBUK];
    int t = threadIdx.x;
    for (int i = t; i < MAXBUK; i += 256) h[i] = 0;
    __syncthreads();
    int e0 = blockIdx.x * A3_TILE + t * 16;
    int src[16], dst[16];
    if (((E & 3) == 0) && (e0 + 15 < E)) {
        const int4* p4s = (const int4*)(ei + e0);
        const int4* p4d = (const int4*)(ei + E + e0);
#pragma unroll
        for (int j4 = 0; j4 < 4; j4++) {
            int4 s4 = p4s[j4];
            int4 d4 = p4d[j4];
            src[j4 * 4 + 0] = s4.x; dst[j4 * 4 + 0] = d4.x;
            src[j4 * 4 + 1] = s4.y; dst[j4 * 4 + 1] = d4.y;
            src[j4 * 4 + 2] = s4.z; dst[j4 * 4 + 2] = d4.z;
            src[j4 * 4 + 3] = s4.w; dst[j4 * 4 + 3] = d4.w;
        }
    } else {
#pragma unroll
        for (int j = 0; j < 16; j++) {
            int e = e0 + j;
            if (e < E) {
                src[j] = ei[e];
                dst[j] = ei[E + e];
            } else {
                dst[j] = -1;
            }
        }
    }
#pragma unroll
    for (int j = 0; j < 16; j++)
        if (dst[j] >= 0) atomicAdd(&h[dst[j] >> 8], 1);
    __syncthreads();
    for (int b = t; b < MAXBUK; b += 256) {
        int c = h[b];
        base[b] = c ? atomicAdd(&bcur[b], c) : 0;
        h[b] = 0;
    }
    __syncthreads();
#pragma unroll
    for (int j = 0; j < 16; j++) {
        if (dst[j] >= 0) {
            int bkt = dst[j] >> 8;
            int r = atomicAdd(&h[bkt], 1);
            pairs[base[bkt] + r] = ((unsigned)(dst[j] & (NPB - 1)) << 24) | (unsigned)src[j];
        }
    }
}

__global__ __launch_bounds__(512) void build_bucket(const unsigned int* __restrict__ pairs,
                                                    const int* __restrict__ bboff,
                                                    int* __restrict__ csr_off,
                                                    int* __restrict__ csr_src,
                                                    float* __restrict__ invd, int N) {
    __shared__ int hist[NPB];
    __shared__ int ssum[NPB];
    __shared__ int cur[NPB];
    int b = blockIdx.x, t = threadIdx.x;
    int gb0 = bboff[b], gb1 = bboff[b + 1];
    int nb0 = b << 8;
    int nn = min(NPB, N - nb0);
    for (int i = t; i < NPB; i += 512) hist[i] = 0;
    __syncthreads();
    for (int i = gb0 + t; i < gb1; i += 512) atomicAdd(&hist[pairs[i] >> 24], 1);
    __syncthreads();
    if (t < NPB) ssum[t] = hist[t];
    __syncthreads();
    for (int off = 1; off < NPB; off <<= 1) {
        int v = 0;
        if (t >= off && t < NPB) v = ssum[t - off];
        __syncthreads();
        if (t < NPB) ssum[t] += v;
        __syncthreads();
    }
    if (t < NPB) {
        int excl = (t == 0) ? 0 : ssum[t - 1];
        cur[t] = excl;
        if (t < nn) {
            csr_off[nb0 + t] = gb0 + excl;
            invd[nb0 + t] = 1.0f / (float)max(hist[t], 1);
        }
    }
    __syncthreads();
    for (int i = gb0 + t; i < gb1; i += 512) {
        unsigned p = pairs[i];
        int ld = p >> 24;
        int pos = atomicAdd(&cur[ld], 1);
        csr_src[gb0 + pos] = (int)(p & 0xFFFFFFu);
    }
}

// ---------------- feature pipeline ----------------
// Activations: fp16 rows inh[n][0..127] = [mean(64) | root(64)], row = 256 B.

__device__ inline void acc8(float* acc, uint4 hv) {
    const __half2* hp = reinterpret_cast<const __half2*>(&hv);
#pragma unroll
    for (int j = 0; j < 4; j++) {
        float2 f = __half22float2(hp[j]);
        acc[2 * j] += f.x;
        acc[2 * j + 1] += f.y;
    }
}

__global__ void pad_x16(const float* __restrict__ x, float* __restrict__ xf,
                        __half* __restrict__ xh, int N) {
    int i = blockIdx.x * blockDim.x + threadIdx.x;
    if (i < N * 16) {
        int n = i >> 4, c = i & 15;
        float v = (c < 13) ? x[n * 13 + c] : 0.f;
        xf[i] = v;
        xh[i] = __float2half(v);
    }
}

// layer 0: fused (gather table is 3.2 MB, L2-resident; K=16 matmul is cheap).
// Writes fp16 root-half of inh1.
__global__ __launch_bounds__(512) void sage_layer0(
    const float* __restrict__ x16f, const __half* __restrict__ x16h,
    const int* __restrict__ off, const int* __restrict__ csr, const float* __restrict__ invd,
    const float* __restrict__ Wl, const float* __restrict__ bl, const float* __restrict__ Wr,
    __half* __restrict__ inh1, int N) {
    __shared__ float wl[16][64];
    __shared__ float wr[16][64];
    __shared__ float bs[64];
    int t = threadIdx.x;
    for (int i = t; i < 16 * 64; i += 512) {
        int k = i >> 6, j = i & 63;
        wl[k][j] = (k < 13) ? Wl[k * 64 + j] : 0.f;
        wr[k][j] = (k < 13) ? Wr[k * 64 + j] : 0.f;
    }
    if (t < 64) bs[t] = bl[t];
    __syncthreads();

    int lane = t & 63, wid = t >> 6;
    int n = blockIdx.x * 8 + wid;
    if (n >= N) return;

    int g = lane >> 1;          // edge subgroup 0..31
    int c8 = (lane & 1) * 8;
    float s = invd[n];
    int e0 = off[n], e1 = off[n + 1];

    float acc[8] = {0, 0, 0, 0, 0, 0, 0, 0};
    int e = e0;
    for (; e + 31 < e1; e += 32) {
        int s0 = csr[e + g];
        uint4 h = *(const uint4*)(x16h + (size_t)s0 * 16 + c8);
        acc8(acc, h);
    }
    if (e + g < e1) {
        int s0 = csr[e + g];
        uint4 h = *(const uint4*)(x16h + (size_t)s0 * 16 + c8);
        acc8(acc, h);
    }
#pragma unroll
    for (int o = 2; o <= 32; o <<= 1) {
#pragma unroll
        for (int j = 0; j < 8; j++) acc[j] += __shfl_xor(acc[j], o);
    }
#pragma unroll
    for (int j = 0; j < 8; j++) acc[j] *= s;

    float4 xv0 = *(const float4*)(x16f + (size_t)n * 16 + c8);
    float4 xv1 = *(const float4*)(x16f + (size_t)n * 16 + c8 + 4);
    float xvf[8] = {xv0.x, xv0.y, xv0.z, xv0.w, xv1.x, xv1.y, xv1.z, xv1.w};

    float out = bs[lane];
#pragma unroll
    for (int j = 0; j < 8; j++) {
#pragma unroll
        for (int l = 0; l < 2; l++) {
            int k = l * 8 + j;
            float a = __shfl(acc[j], l);
            float b = __shfl(xvf[j], l);
            out += a * wl[k][lane] + b * wr[k][lane];
        }
    }
    out = fmaxf(out, 0.f);
    inh1[(size_t)n * 128 + 64 + lane] = __float2half(out);
}

// pure gather/mean: reads inh[.][64..127], writes inh[.][0..63]. No LDS.
__global__ __launch_bounds__(512) void agg_mean(
    __half* __restrict__ inh, const int* __restrict__ off, const int* __restrict__ csr,
    const float* __restrict__ invd, int N) {
    int t = threadIdx.x, lane = t & 63, wid = t >> 6;
    int n = blockIdx.x * 8 + wid;
    if (n >= N) return;

    int g = lane >> 3;          // edge subgroup 0..7
    int c8 = (lane & 7) * 8;    // channel octet
    const __half* srcb = inh + 64;  // root half, row stride 128 halves
    float s = invd[n];
    int e0 = off[n], e1 = off[n + 1];

    float acc[8] = {0, 0, 0, 0, 0, 0, 0, 0};
    int e = e0;
    for (; e + 15 < e1; e += 16) {
        int s0 = csr[e + g];
        int s1 = csr[e + 8 + g];
        uint4 h0 = *(const uint4*)(srcb + (size_t)s0 * 128 + c8);
        uint4 h1 = *(const uint4*)(srcb + (size_t)s1 * 128 + c8);
        acc8(acc, h0);
        acc8(acc, h1);
    }
    if (e + 7 < e1) {
        int s0 = csr[e + g];
        uint4 h0 = *(const uint4*)(srcb + (size_t)s0 * 128 + c8);
        acc8(acc, h0);
        e += 8;
    }
    if (e + g < e1) {
        int s0 = csr[e + g];
        uint4 h0 = *(const uint4*)(srcb + (size_t)s0 * 128 + c8);
        acc8(acc, h0);
    }
#pragma unroll
    for (int o = 8; o <= 32; o <<= 1) {
#pragma unroll
        for (int j = 0; j < 8; j++) acc[j] += __shfl_xor(acc[j], o);
    }
    if (lane < 8) {
        __half2 p[4];
#pragma unroll
        for (int j = 0; j < 4; j++)
            p[j] = __floats2half2_rn(acc[2 * j] * s, acc[2 * j + 1] * s);
        *(uint4*)(inh + (size_t)n * 128 + lane * 8) = *(const uint4*)p;
    }
}

// MFMA GEMM: out = relu([mean|root] @ [Wl;Wr] + b).
// LAST=0: write fp16 root-half of inhNext. LAST=1: fuse layer-3 projection -> s3,r3.
template <int LAST>
__global__ __launch_bounds__(256) void gemm_layer(
    const __half* __restrict__ inh, const float* __restrict__ Wl, const float* __restrict__ bl,
    const float* __restrict__ Wr, __half* __restrict__ inhNext,
    const float* __restrict__ Wl3, const float* __restrict__ bl3, const float* __restrict__ Wr3,
    float* __restrict__ s3, float* __restrict__ r3, int N) {
    __shared__ _Float16 wt[64 * 136];  // wt[c][k], padded stride 136
    __shared__ float bs[64];
    int t = threadIdx.x;
    for (int i = t; i < 8192; i += 256) {
        int k = i >> 6, c = i & 63;
        float v = (k < 64) ? Wl[k * 64 + c] : Wr[(k - 64) * 64 + c];
        wt[c * 136 + k] = (_Float16)v;
    }
    if (t < 64) bs[t] = bl[t];
    __syncthreads();

    int lane = t & 63, wid = t >> 6;
    int n0 = blockIdx.x * 64 + wid * 16;
    int row = lane & 15, kg = lane >> 4;  // kg = 0..3

    // preload 4 A-fragments (K chunks of 32)
    int nrow = min(n0 + row, N - 1);
    const _Float16* abase = (const _Float16*)inh + (size_t)nrow * 128 + kg * 8;
    half8 a[4];
#pragma unroll
    for (int kk = 0; kk < 4; kk++)
        a[kk] = *(const half8*)(abase + kk * 32);

    floatx4 acc[4];
#pragma unroll
    for (int tt = 0; tt < 4; tt++) acc[tt] = (floatx4){0.f, 0.f, 0.f, 0.f};

#pragma unroll
    for (int kk = 0; kk < 4; kk++) {
#pragma unroll
        for (int tt = 0; tt < 4; tt++) {
            half8 b = *(const half8*)&wt[(tt * 16 + row) * 136 + kk * 32 + kg * 8];
            acc[tt] = __builtin_amdgcn_mfma_f32_16x16x32_f16(a[kk], b, acc[tt], 0, 0, 0);
        }
    }

    if (LAST == 0) {
#pragma unroll
        for (int tt = 0; tt < 4; tt++) {
            int col = tt * 16 + row;
            float bias = bs[col];
#pragma unroll
            for (int r = 0; r < 4; r++) {
                int n = n0 + kg * 4 + r;
                float v = fmaxf(acc[tt][r] + bias, 0.f);
                if (n < N) inhNext[(size_t)n * 128 + 64 + col] = __float2half(v);
            }
        }
    } else {
        float wl3v[4], wr3v[4];
#pragma unroll
        for (int tt = 0; tt < 4; tt++) {
            int col = tt * 16 + row;
            wl3v[tt] = Wl3[col];
            wr3v[tt] = Wr3[col];
        }
        float b3 = bl3[0];
        float sp[4], rp[4];
#pragma unroll
        for (int r = 0; r < 4; r++) {
            float spv = 0.f, rpv = 0.f;
#pragma unroll
            for (int tt = 0; tt < 4; tt++) {
                float v = fmaxf(acc[tt][r] + bs[tt * 16 + row], 0.f);
                spv += v * wl3v[tt];
                rpv += v * wr3v[tt];
            }
            sp[r] = spv;
            rp[r] = rpv;
        }
#pragma unroll
        for (int o = 1; o <= 8; o <<= 1) {
#pragma unroll
            for (int r = 0; r < 4; r++) {
                sp[r] += __shfl_xor(sp[r], o);
                rp[r] += __shfl_xor(rp[r], o);
            }
        }
        if (row == 0) {
#pragma unroll
            for (int r = 0; r < 4; r++) {
                int n = n0 + kg * 4 + r;
                if (n < N) {
                    s3[n] = sp[r];
                    r3[n] = rp[r] + b3;
                }
            }
        }
    }
}

__global__ void sage_last_scalar(
    const float* __restrict__ s3, const float* __restrict__ r3, const int* __restrict__ off,
    const int* __restrict__ csr, const float* __restrict__ invd, float* __restrict__ out, int N) {
    int n = blockIdx.x * blockDim.x + threadIdx.x;
    if (n >= N) return;
    int e0 = off[n], e1 = off[n + 1];
    float acc = 0.f;
    int e = e0;
    for (; e + 3 < e1; e += 4) {
        float a0 = s3[csr[e]], a1 = s3[csr[e + 1]], a2 = s3[csr[e + 2]], a3 = s3[csr[e + 3]];
        acc += a0 + a1 + a2 + a3;
    }
    for (; e < e1; e++) acc += s3[csr[e]];
    out[n] = acc * invd[n] + r3[n];
}

// ---------------- launch ----------------

extern "C" void kernel_launch(void* const* d_in, const int* in_sizes, int n_in,
                              void* d_out, int out_size, void* d_ws, size_t ws_size,
                              hipStream_t stream) {
    const float* x0 = (const float*)d_in[0];
    const int* ei = (const int*)d_in[1];
    const float* Wl[4] = {(const float*)d_in[2], (const float*)d_in[5], (const float*)d_in[8],
                          (const float*)d_in[11]};
    const float* bl[4] = {(const float*)d_in[3], (const float*)d_in[6], (const float*)d_in[9],
                          (const float*)d_in[12]};
    const float* Wr[4] = {(const float*)d_in[4], (const float*)d_in[7], (const float*)d_in[10],
                          (const float*)d_in[13]};
    float* out = (float*)d_out;

    const int N = in_sizes[0] / 13;
    const int E = in_sizes[1] / 2;
    const int nbuk = (N + NPB - 1) / NPB;

    char* w = (char*)d_ws;
    auto carve = [&](size_t bytes) {
        void* p = (void*)w;
        w += (bytes + 255) & ~size_t(255);
        return p;
    };
    int* bcnt = (int*)carve((size_t)MAXBUK * 4);
    int* bboff = (int*)carve((size_t)(MAXBUK + 1) * 4);
    int* bcur = (int*)carve((size_t)MAXBUK * 4);
    unsigned int* pairs = (unsigned int*)carve((size_t)E * 4);
    int* csr_off = (int*)carve((size_t)(N + 1) * 4);
    int* csr_src = (int*)carve((size_t)E * 4);
    float* invd = (float*)carve((size_t)N * 4);
    float* x16f = (float*)carve((size_t)N * 16 * 4);
    __half* x16h = (__half*)carve((size_t)N * 16 * 2);
    __half* inh1 = (__half*)carve((size_t)N * 128 * 2);
    __half* inh2 = (__half*)carve((size_t)N * 128 * 2);
    float* s3 = (float*)carve((size_t)N * 4);
    float* r3 = (float*)carve((size_t)N * 4);

    hipMemsetAsync(bcnt, 0, (size_t)MAXBUK * 4, stream);

    bucket_hist<<<1024, 256, 0, stream>>>(ei, E, bcnt, nbuk);
    bucket_scan<<<1, 512, 0, stream>>>(bcnt, bboff, bcur, nbuk, csr_off, N, E);
    partition<<<(E + A3_TILE - 1) / A3_TILE, 256, 0, stream>>>(ei, E, bcur, pairs);
    build_bucket<<<nbuk, 512, 0, stream>>>(pairs, bboff, csr_off, csr_src, invd, N);

    pad_x16<<<(N * 16 + NT - 1) / NT, NT, 0, stream>>>(x0, x16f, x16h, N);

    int nblk8 = (N + 7) / 8;
    int gblk = (N + 63) / 64;
    sage_layer0<<<nblk8, 512, 0, stream>>>(x16f, x16h, csr_off, csr_src, invd,
                                           Wl[0], bl[0], Wr[0], inh1, N);
    agg_mean<<<nblk8, 512, 0, stream>>>(inh1, csr_off, csr_src, invd, N);
    gemm_layer<0><<<gblk, 256, 0, stream>>>(inh1, Wl[1], bl[1], Wr[1], inh2,
                                            nullptr, nullptr, nullptr, nullptr, nullptr, N);
    agg_mean<<<nblk8, 512, 0, stream>>>(inh2, csr_off, csr_src, invd, N);
    gemm_layer<1><<<gblk, 256, 0, stream>>>(inh2, Wl[2], bl[2], Wr[2], nullptr,
                                            Wl[3], bl[3], Wr[3], s3, r3, N);
    sage_last_scalar<<<(N + NT - 1) / NT, NT, 0, stream>>>(s3, r3, csr_off, csr_src, invd, out, N);
}

// Round 7
// 286.458 us; speedup vs baseline: 5.5658x; 1.2074x over previous
//
#include <hip/hip_runtime.h>
#include <hip/hip_fp16.h>

#define NT 256
#define NPB 256        // nodes per bucket (dst >> 8)
#define MAXBUK 512
#define A3_TILE 4096
#define NSTRIP 16      // src strips (src >> 13); 100K nodes -> 13 strips used
#define STRIP_SH 13

typedef _Float16 half8 __attribute__((ext_vector_type(8)));
typedef float floatx4 __attribute__((ext_vector_type(4)));

// ---------------- bucketed CSR build ----------------

__global__ __launch_bounds__(256) void bucket_hist(const int* __restrict__ ei, int E,
                                                   int* __restrict__ bcnt, int nbuk) {
    __shared__ int h[MAXBUK];
    int t = threadIdx.x;
    for (int i = t; i < MAXBUK; i += 256) h[i] = 0;
    __syncthreads();
    const int* dsts = ei + E;
    int i0 = blockIdx.x * 256 + t;
    int stride = gridDim.x * 256;
    if ((E & 3) == 0) {
        const int4* d4 = (const int4*)dsts;
        int n4 = E >> 2;
        for (int i = i0; i < n4; i += stride) {
            int4 v = d4[i];
            atomicAdd(&h[v.x >> 8], 1);
            atomicAdd(&h[v.y >> 8], 1);
            atomicAdd(&h[v.z >> 8], 1);
            atomicAdd(&h[v.w >> 8], 1);
        }
    } else {
        for (int e = i0; e < E; e += stride) atomicAdd(&h[dsts[e] >> 8], 1);
    }
    __syncthreads();
    for (int b = t; b < nbuk; b += 256)
        if (h[b]) atomicAdd(&bcnt[b], h[b]);
}

__global__ __launch_bounds__(512) void bucket_scan(const int* __restrict__ bcnt,
                                                   int* __restrict__ bboff, int* __restrict__ bcur,
                                                   int nbuk, int* __restrict__ csr_off, int N,
                                                   int E) {
    __shared__ int s[512];
    int t = threadIdx.x;
    s[t] = (t < nbuk) ? bcnt[t] : 0;
    __syncthreads();
    for (int off = 1; off < 512; off <<= 1) {
        int v = 0;
        if (t >= off) v = s[t - off];
        __syncthreads();
        s[t] += v;
        __syncthreads();
    }
    int excl = (t == 0) ? 0 : s[t - 1];
    if (t <= nbuk) {
        bboff[t] = excl;
        if (t < nbuk) bcur[t] = excl;
    }
    if (t == 0) csr_off[N] = E;
}

__global__ __launch_bounds__(256) void partition(const int* __restrict__ ei, int E,
                                                 int* __restrict__ bcur,
                                                 unsigned int* __restrict__ pairs) {
    __shared__ int h[MAXBUK];
    __shared__ int base[MAXBUK];
    int t = threadIdx.x;
    for (int i = t; i < MAXBUK; i += 256) h[i] = 0;
    __syncthreads();
    int e0 = blockIdx.x * A3_TILE + t * 16;
    int src[16], dst[16];
    if (((E & 3) == 0) && (e0 + 15 < E)) {
        const int4* p4s = (const int4*)(ei + e0);
        const int4* p4d = (const int4*)(ei + E + e0);
#pragma unroll
        for (int j4 = 0; j4 < 4; j4++) {
            int4 s4 = p4s[j4];
            int4 d4 = p4d[j4];
            src[j4 * 4 + 0] = s4.x; dst[j4 * 4 + 0] = d4.x;
            src[j4 * 4 + 1] = s4.y; dst[j4 * 4 + 1] = d4.y;
            src[j4 * 4 + 2] = s4.z; dst[j4 * 4 + 2] = d4.z;
            src[j4 * 4 + 3] = s4.w; dst[j4 * 4 + 3] = d4.w;
        }
    } else {
#pragma unroll
        for (int j = 0; j < 16; j++) {
            int e = e0 + j;
            if (e < E) {
                src[j] = ei[e];
                dst[j] = ei[E + e];
            } else {
                dst[j] = -1;
            }
        }
    }
#pragma unroll
    for (int j = 0; j < 16; j++)
        if (dst[j] >= 0) atomicAdd(&h[dst[j] >> 8], 1);
    __syncthreads();
    for (int b = t; b < MAXBUK; b += 256) {
        int c = h[b];
        base[b] = c ? atomicAdd(&bcur[b], c) : 0;
        h[b] = 0;
    }
    __syncthreads();
#pragma unroll
    for (int j = 0; j < 16; j++) {
        if (dst[j] >= 0) {
            int bkt = dst[j] >> 8;
            int r = atomicAdd(&h[bkt], 1);
            pairs[base[bkt] + r] = ((unsigned)(dst[j] & (NPB - 1)) << 24) | (unsigned)src[j];
        }
    }
}

// per-(node,strip) cursors -> each node's neighbor list sorted by src strip
__global__ __launch_bounds__(512) void build_bucket(const unsigned int* __restrict__ pairs,
                                                    const int* __restrict__ bboff,
                                                    int* __restrict__ csr_off,
                                                    int* __restrict__ csr_src,
                                                    float* __restrict__ invd, int N) {
    __shared__ int h2[NPB * NSTRIP];  // 4096 counters: [node][strip]
    __shared__ int tsum[512];
    int b = blockIdx.x, t = threadIdx.x;
    int gb0 = bboff[b], gb1 = bboff[b + 1];
    int nb0 = b << 8;
    int nn = min(NPB, N - nb0);
    for (int i = t; i < NPB * NSTRIP; i += 512) h2[i] = 0;
    __syncthreads();
    for (int i = gb0 + t; i < gb1; i += 512) {
        unsigned p = pairs[i];
        int ld = p >> 24;
        int st = (int)((p & 0xFFFFFFu) >> STRIP_SH);
        atomicAdd(&h2[ld * NSTRIP + st], 1);
    }
    __syncthreads();
    // per-node degree -> invd (reads h2 before it is overwritten by the scan)
    if (t < nn) {
        int d = 0;
#pragma unroll
        for (int ss = 0; ss < NSTRIP; ss++) d += h2[t * NSTRIP + ss];
        invd[nb0 + t] = 1.0f / (float)max(d, 1);
    }
    // block scan of 4096 entries: thread t owns [t*8, t*8+8)
    int v[8];
    int loc = 0;
#pragma unroll
    for (int j = 0; j < 8; j++) {
        v[j] = h2[t * 8 + j];
        loc += v[j];
    }
    tsum[t] = loc;
    __syncthreads();
    for (int off = 1; off < 512; off <<= 1) {
        int xv = 0;
        if (t >= off) xv = tsum[t - off];
        __syncthreads();
        tsum[t] += xv;
        __syncthreads();
    }
    int run = (t == 0) ? 0 : tsum[t - 1];
#pragma unroll
    for (int j = 0; j < 8; j++) {
        h2[t * 8 + j] = run;  // exclusive prefix -> becomes cursor
        run += v[j];
    }
    __syncthreads();
    if (t < nn) csr_off[nb0 + t] = gb0 + h2[t * NSTRIP];
    __syncthreads();
    for (int i = gb0 + t; i < gb1; i += 512) {
        unsigned p = pairs[i];
        int ld = p >> 24;
        unsigned srcv = p & 0xFFFFFFu;
        int st = (int)(srcv >> STRIP_SH);
        int pos = atomicAdd(&h2[ld * NSTRIP + st], 1);
        csr_src[gb0 + pos] = (int)srcv;
    }
}

// ---------------- feature pipeline ----------------
// inh rows (fp16): [mean(64) | root(64)], 256 B. inh0 rows: [mean16 | root16], 64 B.

__device__ inline void acc8(float* acc, uint4 hv) {
    const __half2* hp = reinterpret_cast<const __half2*>(&hv);
#pragma unroll
    for (int j = 0; j < 4; j++) {
        float2 f = __half22float2(hp[j]);
        acc[2 * j] += f.x;
        acc[2 * j + 1] += f.y;
    }
}

__device__ inline void acc4(float* acc, uint2 hv) {
    const __half2* hp = reinterpret_cast<const __half2*>(&hv);
#pragma unroll
    for (int j = 0; j < 2; j++) {
        float2 f = __half22float2(hp[j]);
        acc[2 * j] += f.x;
        acc[2 * j + 1] += f.y;
    }
}

// pack x [N,13] -> fp16 gather table [N,16] + root half of inh0 [N,32]
__global__ void pad_x(const float* __restrict__ x, __half* __restrict__ xh,
                      __half* __restrict__ inh0, int N) {
    int i = blockIdx.x * blockDim.x + threadIdx.x;
    if (i < N * 16) {
        int n = i >> 4, c = i & 15;
        float v = (c < 13) ? x[n * 13 + c] : 0.f;
        __half h = __float2half(v);
        xh[i] = h;
        inh0[(size_t)n * 32 + 16 + c] = h;
    }
}

// layer-0 aggregation: 16-ch gather, 4 lanes/edge (uint2), 16 edges/iter base
__global__ __launch_bounds__(512) void agg16(
    const __half* __restrict__ x16h, const int* __restrict__ off, const int* __restrict__ csr,
    const float* __restrict__ invd, __half* __restrict__ inh0, int N) {
    int t = threadIdx.x, lane = t & 63, wid = t >> 6;
    int n = blockIdx.x * 8 + wid;
    if (n >= N) return;

    int g = lane >> 2;        // edge subgroup 0..15
    int c4 = (lane & 3) * 4;  // 4 channels per lane
    float s = invd[n];
    int e0 = off[n], e1 = off[n + 1];

    float acc[4] = {0, 0, 0, 0};
    int e = e0;
    for (; e + 31 < e1; e += 32) {
        int s0 = csr[e + g];
        int s1 = csr[e + 16 + g];
        uint2 h0 = *(const uint2*)(x16h + (size_t)s0 * 16 + c4);
        uint2 h1 = *(const uint2*)(x16h + (size_t)s1 * 16 + c4);
        acc4(acc, h0);
        acc4(acc, h1);
    }
    if (e + 15 < e1) {
        uint2 h0 = *(const uint2*)(x16h + (size_t)csr[e + g] * 16 + c4);
        acc4(acc, h0);
        e += 16;
    }
    if (e + g < e1) {
        uint2 h0 = *(const uint2*)(x16h + (size_t)csr[e + g] * 16 + c4);
        acc4(acc, h0);
    }
#pragma unroll
    for (int o = 4; o <= 32; o <<= 1) {
#pragma unroll
        for (int j = 0; j < 4; j++) acc[j] += __shfl_xor(acc[j], o);
    }
    if (lane < 4) {
        __half2 p[2];
        p[0] = __floats2half2_rn(acc[0] * s, acc[1] * s);
        p[1] = __floats2half2_rn(acc[2] * s, acc[3] * s);
        *(uint2*)(inh0 + (size_t)n * 32 + lane * 4) = *(const uint2*)p;
    }
}

// layer-0 GEMM: K=32 MFMA, writes fp16 root half of inh1
__global__ __launch_bounds__(256) void gemm0(
    const __half* __restrict__ inh0, const float* __restrict__ Wl, const float* __restrict__ bl,
    const float* __restrict__ Wr, __half* __restrict__ inh1, int N) {
    __shared__ _Float16 wt[64 * 40];  // wt[c][k], k 0..31, stride 40
    __shared__ float bs[64];
    int t = threadIdx.x;
    for (int i = t; i < 64 * 32; i += 256) {
        int k = i >> 6, c = i & 63;
        float v;
        if (k < 16) v = (k < 13) ? Wl[k * 64 + c] : 0.f;
        else {
            int kk = k - 16;
            v = (kk < 13) ? Wr[kk * 64 + c] : 0.f;
        }
        wt[c * 40 + k] = (_Float16)v;
    }
    if (t < 64) bs[t] = bl[t];
    __syncthreads();

    int lane = t & 63, wid = t >> 6;
    int n0 = blockIdx.x * 64 + wid * 16;
    int row = lane & 15, kg = lane >> 4;

    int nrow = min(n0 + row, N - 1);
    half8 a = *(const half8*)((const _Float16*)inh0 + (size_t)nrow * 32 + kg * 8);

    floatx4 acc[4];
#pragma unroll
    for (int tt = 0; tt < 4; tt++) acc[tt] = (floatx4){0.f, 0.f, 0.f, 0.f};
#pragma unroll
    for (int tt = 0; tt < 4; tt++) {
        half8 b = *(const half8*)&wt[(tt * 16 + row) * 40 + kg * 8];
        acc[tt] = __builtin_amdgcn_mfma_f32_16x16x32_f16(a, b, acc[tt], 0, 0, 0);
    }
#pragma unroll
    for (int tt = 0; tt < 4; tt++) {
        int col = tt * 16 + row;
        float bias = bs[col];
#pragma unroll
        for (int r = 0; r < 4; r++) {
            int n = n0 + kg * 4 + r;
            if (n < N) inh1[(size_t)n * 128 + 64 + col] = __float2half(fmaxf(acc[tt][r] + bias, 0.f));
        }
    }
}

// 64-ch gather/mean: 4 outstanding 128B loads per iter (32 edges)
__global__ __launch_bounds__(512) void agg_mean(
    __half* __restrict__ inh, const int* __restrict__ off, const int* __restrict__ csr,
    const float* __restrict__ invd, int N) {
    int t = threadIdx.x, lane = t & 63, wid = t >> 6;
    int n = blockIdx.x * 8 + wid;
    if (n >= N) return;

    int g = lane >> 3;
    int c8 = (lane & 7) * 8;
    const __half* srcb = inh + 64;
    float s = invd[n];
    int e0 = off[n], e1 = off[n + 1];

    float acc[8] = {0, 0, 0, 0, 0, 0, 0, 0};
    int e = e0;
    for (; e + 31 < e1; e += 32) {
        int s0 = csr[e + g];
        int s1 = csr[e + 8 + g];
        int s2 = csr[e + 16 + g];
        int s3 = csr[e + 24 + g];
        uint4 h0 = *(const uint4*)(srcb + (size_t)s0 * 128 + c8);
        uint4 h1 = *(const uint4*)(srcb + (size_t)s1 * 128 + c8);
        uint4 h2 = *(const uint4*)(srcb + (size_t)s2 * 128 + c8);
        uint4 h3 = *(const uint4*)(srcb + (size_t)s3 * 128 + c8);
        acc8(acc, h0);
        acc8(acc, h1);
        acc8(acc, h2);
        acc8(acc, h3);
    }
    if (e + 15 < e1) {
        int s0 = csr[e + g];
        int s1 = csr[e + 8 + g];
        uint4 h0 = *(const uint4*)(srcb + (size_t)s0 * 128 + c8);
        uint4 h1 = *(const uint4*)(srcb + (size_t)s1 * 128 + c8);
        acc8(acc, h0);
        acc8(acc, h1);
        e += 16;
    }
    if (e + 7 < e1) {
        uint4 h0 = *(const uint4*)(srcb + (size_t)csr[e + g] * 128 + c8);
        acc8(acc, h0);
        e += 8;
    }
    if (e + g < e1) {
        uint4 h0 = *(const uint4*)(srcb + (size_t)csr[e + g] * 128 + c8);
        acc8(acc, h0);
    }
#pragma unroll
    for (int o = 8; o <= 32; o <<= 1) {
#pragma unroll
        for (int j = 0; j < 8; j++) acc[j] += __shfl_xor(acc[j], o);
    }
    if (lane < 8) {
        __half2 p[4];
#pragma unroll
        for (int j = 0; j < 4; j++)
            p[j] = __floats2half2_rn(acc[2 * j] * s, acc[2 * j + 1] * s);
        *(uint4*)(inh + (size_t)n * 128 + lane * 8) = *(const uint4*)p;
    }
}

// MFMA GEMM layers 1/2 (LAST=1 fuses layer-3 projection -> s3,r3)
template <int LAST>
__global__ __launch_bounds__(256) void gemm_layer(
    const __half* __restrict__ inh, const float* __restrict__ Wl, const float* __restrict__ bl,
    const float* __restrict__ Wr, __half* __restrict__ inhNext,
    const float* __restrict__ Wl3, const float* __restrict__ bl3, const float* __restrict__ Wr3,
    float* __restrict__ s3, float* __restrict__ r3, int N) {
    __shared__ _Float16 wt[64 * 136];
    __shared__ float bs[64];
    int t = threadIdx.x;
    for (int i = t; i < 8192; i += 256) {
        int k = i >> 6, c = i & 63;
        float v = (k < 64) ? Wl[k * 64 + c] : Wr[(k - 64) * 64 + c];
        wt[c * 136 + k] = (_Float16)v;
    }
    if (t < 64) bs[t] = bl[t];
    __syncthreads();

    int lane = t & 63, wid = t >> 6;
    int n0 = blockIdx.x * 64 + wid * 16;
    int row = lane & 15, kg = lane >> 4;

    int nrow = min(n0 + row, N - 1);
    const _Float16* abase = (const _Float16*)inh + (size_t)nrow * 128 + kg * 8;
    half8 a[4];
#pragma unroll
    for (int kk = 0; kk < 4; kk++) a[kk] = *(const half8*)(abase + kk * 32);

    floatx4 acc[4];
#pragma unroll
    for (int tt = 0; tt < 4; tt++) acc[tt] = (floatx4){0.f, 0.f, 0.f, 0.f};

#pragma unroll
    for (int kk = 0; kk < 4; kk++) {
#pragma unroll
        for (int tt = 0; tt < 4; tt++) {
            half8 b = *(const half8*)&wt[(tt * 16 + row) * 136 + kk * 32 + kg * 8];
            acc[tt] = __builtin_amdgcn_mfma_f32_16x16x32_f16(a[kk], b, acc[tt], 0, 0, 0);
        }
    }

    if (LAST == 0) {
#pragma unroll
        for (int tt = 0; tt < 4; tt++) {
            int col = tt * 16 + row;
            float bias = bs[col];
#pragma unroll
            for (int r = 0; r < 4; r++) {
                int n = n0 + kg * 4 + r;
                float v = fmaxf(acc[tt][r] + bias, 0.f);
                if (n < N) inhNext[(size_t)n * 128 + 64 + col] = __float2half(v);
            }
        }
    } else {
        float wl3v[4], wr3v[4];
#pragma unroll
        for (int tt = 0; tt < 4; tt++) {
            int col = tt * 16 + row;
            wl3v[tt] = Wl3[col];
            wr3v[tt] = Wr3[col];
        }
        float b3 = bl3[0];
        float sp[4], rp[4];
#pragma unroll
        for (int r = 0; r < 4; r++) {
            float spv = 0.f, rpv = 0.f;
#pragma unroll
            for (int tt = 0; tt < 4; tt++) {
                float v = fmaxf(acc[tt][r] + bs[tt * 16 + row], 0.f);
                spv += v * wl3v[tt];
                rpv += v * wr3v[tt];
            }
            sp[r] = spv;
            rp[r] = rpv;
        }
#pragma unroll
        for (int o = 1; o <= 8; o <<= 1) {
#pragma unroll
            for (int r = 0; r < 4; r++) {
                sp[r] += __shfl_xor(sp[r], o);
                rp[r] += __shfl_xor(rp[r], o);
            }
        }
        if (row == 0) {
#pragma unroll
            for (int r = 0; r < 4; r++) {
                int n = n0 + kg * 4 + r;
                if (n < N) {
                    s3[n] = sp[r];
                    r3[n] = rp[r] + b3;
                }
            }
        }
    }
}

__global__ void sage_last_scalar(
    const float* __restrict__ s3, const float* __restrict__ r3, const int* __restrict__ off,
    const int* __restrict__ csr, const float* __restrict__ invd, float* __restrict__ out, int N) {
    int n = blockIdx.x * blockDim.x + threadIdx.x;
    if (n >= N) return;
    int e0 = off[n], e1 = off[n + 1];
    float acc = 0.f;
    int e = e0;
    for (; e + 3 < e1; e += 4) {
        float a0 = s3[csr[e]], a1 = s3[csr[e + 1]], a2 = s3[csr[e + 2]], a3 = s3[csr[e + 3]];
        acc += a0 + a1 + a2 + a3;
    }
    for (; e < e1; e++) acc += s3[csr[e]];
    out[n] = acc * invd[n] + r3[n];
}

// ---------------- launch ----------------

extern "C" void kernel_launch(void* const* d_in, const int* in_sizes, int n_in,
                              void* d_out, int out_size, void* d_ws, size_t ws_size,
                              hipStream_t stream) {
    const float* x0 = (const float*)d_in[0];
    const int* ei = (const int*)d_in[1];
    const float* Wl[4] = {(const float*)d_in[2], (const float*)d_in[5], (const float*)d_in[8],
                          (const float*)d_in[11]};
    const float* bl[4] = {(const float*)d_in[3], (const float*)d_in[6], (const float*)d_in[9],
                          (const float*)d_in[12]};
    const float* Wr[4] = {(const float*)d_in[4], (const float*)d_in[7], (const float*)d_in[10],
                          (const float*)d_in[13]};
    float* out = (float*)d_out;

    const int N = in_sizes[0] / 13;
    const int E = in_sizes[1] / 2;
    const int nbuk = (N + NPB - 1) / NPB;

    char* w = (char*)d_ws;
    auto carve = [&](size_t bytes) {
        void* p = (void*)w;
        w += (bytes + 255) & ~size_t(255);
        return p;
    };
    int* bcnt = (int*)carve((size_t)MAXBUK * 4);
    int* bboff = (int*)carve((size_t)(MAXBUK + 1) * 4);
    int* bcur = (int*)carve((size_t)MAXBUK * 4);
    unsigned int* pairs = (unsigned int*)carve((size_t)E * 4);
    int* csr_off = (int*)carve((size_t)(N + 1) * 4);
    int* csr_src = (int*)carve((size_t)E * 4);
    float* invd = (float*)carve((size_t)N * 4);
    __half* x16h = (__half*)carve((size_t)N * 16 * 2);
    __half* inh0 = (__half*)carve((size_t)N * 32 * 2);
    __half* inh1 = (__half*)carve((size_t)N * 128 * 2);
    __half* inh2 = (__half*)carve((size_t)N * 128 * 2);
    float* s3 = (float*)carve((size_t)N * 4);
    float* r3 = (float*)carve((size_t)N * 4);

    hipMemsetAsync(bcnt, 0, (size_t)MAXBUK * 4, stream);

    bucket_hist<<<1024, 256, 0, stream>>>(ei, E, bcnt, nbuk);
    bucket_scan<<<1, 512, 0, stream>>>(bcnt, bboff, bcur, nbuk, csr_off, N, E);
    partition<<<(E + A3_TILE - 1) / A3_TILE, 256, 0, stream>>>(ei, E, bcur, pairs);
    build_bucket<<<nbuk, 512, 0, stream>>>(pairs, bboff, csr_off, csr_src, invd, N);

    pad_x<<<(N * 16 + NT - 1) / NT, NT, 0, stream>>>(x0, x16h, inh0, N);

    int nblk8 = (N + 7) / 8;
    int gblk = (N + 63) / 64;
    agg16<<<nblk8, 512, 0, stream>>>(x16h, csr_off, csr_src, invd, inh0, N);
    gemm0<<<gblk, 256, 0, stream>>>(inh0, Wl[0], bl[0], Wr[0], inh1, N);
    agg_mean<<<nblk8, 512, 0, stream>>>(inh1, csr_off, csr_src, invd, N);
    gemm_layer<0><<<gblk, 256, 0, stream>>>(inh1, Wl[1], bl[1], Wr[1], inh2,
                                            nullptr, nullptr, nullptr, nullptr, nullptr, N);
    agg_mean<<<nblk8, 512, 0, stream>>>(inh2, csr_off, csr_src, invd, N);
    gemm_layer<1><<<gblk, 256, 0, stream>>>(inh2, Wl[2], bl[2], Wr[2], nullptr,
                                            Wl[3], bl[3], Wr[3], s3, r3, N);
    sage_last_scalar<<<(N + NT - 1) / NT, NT, 0, stream>>>(s3, r3, csr_off, csr_src, invd, out, N);
}

// Round 8
// 273.283 us; speedup vs baseline: 5.8341x; 1.0482x over previous
//
#include <hip/hip_runtime.h>
#include <hip/hip_fp16.h>

#define NT 256
#define NPB 256        // nodes per bucket (dst >> 8)
#define MAXBUK 512
#define A3_TILE 4096
#define NSTRIP 16
#define STRIP_SH 13

typedef _Float16 half8 __attribute__((ext_vector_type(8)));
typedef float floatx4 __attribute__((ext_vector_type(4)));

// ---------------- bucketed CSR build (unchanged, working) ----------------

__global__ __launch_bounds__(256) void bucket_hist(const int* __restrict__ ei, int E,
                                                   int* __restrict__ bcnt, int nbuk) {
    __shared__ int h[MAXBUK];
    int t = threadIdx.x;
    for (int i = t; i < MAXBUK; i += 256) h[i] = 0;
    __syncthreads();
    const int* dsts = ei + E;
    int i0 = blockIdx.x * 256 + t;
    int stride = gridDim.x * 256;
    if ((E & 3) == 0) {
        const int4* d4 = (const int4*)dsts;
        int n4 = E >> 2;
        for (int i = i0; i < n4; i += stride) {
            int4 v = d4[i];
            atomicAdd(&h[v.x >> 8], 1);
            atomicAdd(&h[v.y >> 8], 1);
            atomicAdd(&h[v.z >> 8], 1);
            atomicAdd(&h[v.w >> 8], 1);
        }
    } else {
        for (int e = i0; e < E; e += stride) atomicAdd(&h[dsts[e] >> 8], 1);
    }
    __syncthreads();
    for (int b = t; b < nbuk; b += 256)
        if (h[b]) atomicAdd(&bcnt[b], h[b]);
}

__global__ __launch_bounds__(512) void bucket_scan(const int* __restrict__ bcnt,
                                                   int* __restrict__ bboff, int* __restrict__ bcur,
                                                   int nbuk, int* __restrict__ csr_off, int N,
                                                   int E) {
    __shared__ int s[512];
    int t = threadIdx.x;
    s[t] = (t < nbuk) ? bcnt[t] : 0;
    __syncthreads();
    for (int off = 1; off < 512; off <<= 1) {
        int v = 0;
        if (t >= off) v = s[t - off];
        __syncthreads();
        s[t] += v;
        __syncthreads();
    }
    int excl = (t == 0) ? 0 : s[t - 1];
    if (t <= nbuk) {
        bboff[t] = excl;
        if (t < nbuk) bcur[t] = excl;
    }
    if (t == 0) csr_off[N] = E;
}

__global__ __launch_bounds__(256) void partition(const int* __restrict__ ei, int E,
                                                 int* __restrict__ bcur,
                                                 unsigned int* __restrict__ pairs) {
    __shared__ int h[MAXBUK];
    __shared__ int base[MAXBUK];
    int t = threadIdx.x;
    for (int i = t; i < MAXBUK; i += 256) h[i] = 0;
    __syncthreads();
    int e0 = blockIdx.x * A3_TILE + t * 16;
    int src[16], dst[16];
    if (((E & 3) == 0) && (e0 + 15 < E)) {
        const int4* p4s = (const int4*)(ei + e0);
        const int4* p4d = (const int4*)(ei + E + e0);
#pragma unroll
        for (int j4 = 0; j4 < 4; j4++) {
            int4 s4 = p4s[j4];
            int4 d4 = p4d[j4];
            src[j4 * 4 + 0] = s4.x; dst[j4 * 4 + 0] = d4.x;
            src[j4 * 4 + 1] = s4.y; dst[j4 * 4 + 1] = d4.y;
            src[j4 * 4 + 2] = s4.z; dst[j4 * 4 + 2] = d4.z;
            src[j4 * 4 + 3] = s4.w; dst[j4 * 4 + 3] = d4.w;
        }
    } else {
#pragma unroll
        for (int j = 0; j < 16; j++) {
            int e = e0 + j;
            if (e < E) {
                src[j] = ei[e];
                dst[j] = ei[E + e];
            } else {
                dst[j] = -1;
            }
        }
    }
#pragma unroll
    for (int j = 0; j < 16; j++)
        if (dst[j] >= 0) atomicAdd(&h[dst[j] >> 8], 1);
    __syncthreads();
    for (int b = t; b < MAXBUK; b += 256) {
        int c = h[b];
        base[b] = c ? atomicAdd(&bcur[b], c) : 0;
        h[b] = 0;
    }
    __syncthreads();
#pragma unroll
    for (int j = 0; j < 16; j++) {
        if (dst[j] >= 0) {
            int bkt = dst[j] >> 8;
            int r = atomicAdd(&h[bkt], 1);
            pairs[base[bkt] + r] = ((unsigned)(dst[j] & (NPB - 1)) << 24) | (unsigned)src[j];
        }
    }
}

__global__ __launch_bounds__(512) void build_bucket(const unsigned int* __restrict__ pairs,
                                                    const int* __restrict__ bboff,
                                                    int* __restrict__ csr_off,
                                                    int* __restrict__ csr_src,
                                                    float* __restrict__ invd, int N) {
    __shared__ int h2[NPB * NSTRIP];
    __shared__ int tsum[512];
    int b = blockIdx.x, t = threadIdx.x;
    int gb0 = bboff[b], gb1 = bboff[b + 1];
    int nb0 = b << 8;
    int nn = min(NPB, N - nb0);
    for (int i = t; i < NPB * NSTRIP; i += 512) h2[i] = 0;
    __syncthreads();
    for (int i = gb0 + t; i < gb1; i += 512) {
        unsigned p = pairs[i];
        int ld = p >> 24;
        int st = (int)((p & 0xFFFFFFu) >> STRIP_SH);
        atomicAdd(&h2[ld * NSTRIP + st], 1);
    }
    __syncthreads();
    if (t < nn) {
        int d = 0;
#pragma unroll
        for (int ss = 0; ss < NSTRIP; ss++) d += h2[t * NSTRIP + ss];
        invd[nb0 + t] = 1.0f / (float)max(d, 1);
    }
    int v[8];
    int loc = 0;
#pragma unroll
    for (int j = 0; j < 8; j++) {
        v[j] = h2[t * 8 + j];
        loc += v[j];
    }
    tsum[t] = loc;
    __syncthreads();
    for (int off = 1; off < 512; off <<= 1) {
        int xv = 0;
        if (t >= off) xv = tsum[t - off];
        __syncthreads();
        tsum[t] += xv;
        __syncthreads();
    }
    int run = (t == 0) ? 0 : tsum[t - 1];
#pragma unroll
    for (int j = 0; j < 8; j++) {
        h2[t * 8 + j] = run;
        run += v[j];
    }
    __syncthreads();
    if (t < nn) csr_off[nb0 + t] = gb0 + h2[t * NSTRIP];
    __syncthreads();
    for (int i = gb0 + t; i < gb1; i += 512) {
        unsigned p = pairs[i];
        int ld = p >> 24;
        unsigned srcv = p & 0xFFFFFFu;
        int st = (int)(srcv >> STRIP_SH);
        int pos = atomicAdd(&h2[ld * NSTRIP + st], 1);
        csr_src[gb0 + pos] = (int)srcv;
    }
}

// ---------------- feature pipeline ----------------
// xroot0: [N][16] fp16 (layer-0 gather table). xroot1/2: [N][64] fp16.

__device__ inline void acc8(float* acc, uint4 hv) {
    const __half2* hp = reinterpret_cast<const __half2*>(&hv);
#pragma unroll
    for (int j = 0; j < 4; j++) {
        float2 f = __half22float2(hp[j]);
        acc[2 * j] += f.x;
        acc[2 * j + 1] += f.y;
    }
}

__device__ inline void acc4v(float* acc, uint2 hv) {
    const __half2* hp = reinterpret_cast<const __half2*>(&hv);
#pragma unroll
    for (int j = 0; j < 2; j++) {
        float2 f = __half22float2(hp[j]);
        acc[2 * j] += f.x;
        acc[2 * j + 1] += f.y;
    }
}

__global__ void pad_x(const float* __restrict__ x, __half* __restrict__ xroot0, int N) {
    int i = blockIdx.x * blockDim.x + threadIdx.x;
    if (i < N * 16) {
        int n = i >> 4, c = i & 15;
        float v = (c < 13) ? x[n * 13 + c] : 0.f;
        xroot0[i] = __float2half(v);
    }
}

// fused layer 0: agg(16ch) -> LDS -> K=32 MFMA -> xroot1
__global__ __launch_bounds__(512) void fused0(
    const __half* __restrict__ xroot0, const int* __restrict__ off, const int* __restrict__ csr,
    const float* __restrict__ invd, const float* __restrict__ Wl, const float* __restrict__ bl,
    const float* __restrict__ Wr, __half* __restrict__ xroot1, int N) {
    __shared__ _Float16 act[64 * 40];   // [node][k: mean16|root16] stride 40
    __shared__ _Float16 wt[64 * 40];    // [col][k]
    __shared__ float bs[64];
    int t = threadIdx.x;
    for (int i = t; i < 2048; i += 512) {
        int k = i >> 6, c = i & 63;
        float v;
        if (k < 16) v = (k < 13) ? Wl[k * 64 + c] : 0.f;
        else {
            int kk = k - 16;
            v = (kk < 13) ? Wr[kk * 64 + c] : 0.f;
        }
        wt[c * 40 + k] = (_Float16)v;
    }
    if (t < 64) bs[t] = bl[t];
    int n0 = blockIdx.x * 64;
    // root copy: 256 threads cover 64 nodes x 16 ch
    if (t < 256) {
        int node = t >> 2, c4 = (t & 3) * 4;
        int n = min(n0 + node, N - 1);
        uint2 rv = *(const uint2*)(xroot0 + (size_t)n * 16 + c4);
        *(uint2*)&act[node * 40 + 16 + c4] = rv;
    }
    int lane = t & 63, wid = t >> 6;
    int g = lane >> 2, c4 = (lane & 3) * 4;  // 16 edges/instr, 4 ch/lane
#pragma unroll 1
    for (int rr = 0; rr < 8; rr++) {
        int nloc = rr * 8 + wid;
        int n = min(n0 + nloc, N - 1);
        float sc = invd[n];
        int e0 = off[n], e1 = off[n + 1];
        float acc[4] = {0, 0, 0, 0};
        int e = e0;
        for (; e + 31 < e1; e += 32) {
            int s0 = csr[e + g];
            int s1 = csr[e + 16 + g];
            uint2 h0 = *(const uint2*)(xroot0 + (size_t)s0 * 16 + c4);
            uint2 h1 = *(const uint2*)(xroot0 + (size_t)s1 * 16 + c4);
            acc4v(acc, h0);
            acc4v(acc, h1);
        }
        if (e + 15 < e1) {
            uint2 h0 = *(const uint2*)(xroot0 + (size_t)csr[e + g] * 16 + c4);
            acc4v(acc, h0);
            e += 16;
        }
        if (e + g < e1) {
            uint2 h0 = *(const uint2*)(xroot0 + (size_t)csr[e + g] * 16 + c4);
            acc4v(acc, h0);
        }
#pragma unroll
        for (int o = 4; o <= 32; o <<= 1) {
#pragma unroll
            for (int j = 0; j < 4; j++) acc[j] += __shfl_xor(acc[j], o);
        }
        if (lane < 4) {
            __half2 p[2];
            p[0] = __floats2half2_rn(acc[0] * sc, acc[1] * sc);
            p[1] = __floats2half2_rn(acc[2] * sc, acc[3] * sc);
            *(uint2*)&act[nloc * 40 + lane * 4] = *(const uint2*)p;
        }
    }
    __syncthreads();
    if (wid < 4) {
        int row = lane & 15, kg = lane >> 4;
        half8 a = *(const half8*)&act[(wid * 16 + row) * 40 + kg * 8];
        floatx4 ac[4];
#pragma unroll
        for (int tt = 0; tt < 4; tt++) ac[tt] = (floatx4){0.f, 0.f, 0.f, 0.f};
#pragma unroll
        for (int tt = 0; tt < 4; tt++) {
            half8 b = *(const half8*)&wt[(tt * 16 + row) * 40 + kg * 8];
            ac[tt] = __builtin_amdgcn_mfma_f32_16x16x32_f16(a, b, ac[tt], 0, 0, 0);
        }
#pragma unroll
        for (int tt = 0; tt < 4; tt++) {
            int col = tt * 16 + row;
            float bias = bs[col];
#pragma unroll
            for (int r = 0; r < 4; r++) {
                int n = n0 + wid * 16 + kg * 4 + r;
                if (n < N)
                    xroot1[(size_t)n * 64 + col] = __float2half(fmaxf(ac[tt][r] + bias, 0.f));
            }
        }
    }
}

// fused layers 1/2: agg(64ch)->LDS -> K=128 MFMA. LAST=1 fuses layer-3 projection.
template <int LAST>
__global__ __launch_bounds__(512) void fused_layer(
    const __half* __restrict__ xroot, const int* __restrict__ off, const int* __restrict__ csr,
    const float* __restrict__ invd, const float* __restrict__ Wl, const float* __restrict__ bl,
    const float* __restrict__ Wr, __half* __restrict__ xnext,
    const float* __restrict__ Wl3, const float* __restrict__ bl3, const float* __restrict__ Wr3,
    float* __restrict__ s3, float* __restrict__ r3, int N) {
    __shared__ _Float16 act[64 * 136];  // [node][k: mean64|root64] stride 136
    __shared__ _Float16 wt[64 * 136];   // [col][k]
    __shared__ float bs[64];
    int t = threadIdx.x;
    for (int i = t; i < 8192; i += 512) {
        int k = i >> 6, c = i & 63;
        float v = (k < 64) ? Wl[k * 64 + c] : Wr[(k - 64) * 64 + c];
        wt[c * 136 + k] = (_Float16)v;
    }
    if (t < 64) bs[t] = bl[t];
    int n0 = blockIdx.x * 64;
    // root copy: 512 threads cover 64 nodes x 64 ch (8 ch each)
    {
        int node = t >> 3, cc8 = (t & 7) * 8;
        int n = min(n0 + node, N - 1);
        uint4 rv = *(const uint4*)(xroot + (size_t)n * 64 + cc8);
        *(uint4*)&act[node * 136 + 64 + cc8] = rv;
    }
    int lane = t & 63, wid = t >> 6;
    int g = lane >> 3, c8 = (lane & 7) * 8;
#pragma unroll 1
    for (int rr = 0; rr < 8; rr++) {
        int nloc = rr * 8 + wid;
        int n = min(n0 + nloc, N - 1);
        float sc = invd[n];
        int e0 = off[n], e1 = off[n + 1];
        float acc[8] = {0, 0, 0, 0, 0, 0, 0, 0};
        int e = e0;
        for (; e + 31 < e1; e += 32) {
            int s0 = csr[e + g];
            int s1 = csr[e + 8 + g];
            int s2 = csr[e + 16 + g];
            int s3v = csr[e + 24 + g];
            uint4 h0 = *(const uint4*)(xroot + (size_t)s0 * 64 + c8);
            uint4 h1 = *(const uint4*)(xroot + (size_t)s1 * 64 + c8);
            uint4 h2 = *(const uint4*)(xroot + (size_t)s2 * 64 + c8);
            uint4 h3 = *(const uint4*)(xroot + (size_t)s3v * 64 + c8);
            acc8(acc, h0);
            acc8(acc, h1);
            acc8(acc, h2);
            acc8(acc, h3);
        }
        if (e + 15 < e1) {
            int s0 = csr[e + g];
            int s1 = csr[e + 8 + g];
            uint4 h0 = *(const uint4*)(xroot + (size_t)s0 * 64 + c8);
            uint4 h1 = *(const uint4*)(xroot + (size_t)s1 * 64 + c8);
            acc8(acc, h0);
            acc8(acc, h1);
            e += 16;
        }
        if (e + 7 < e1) {
            uint4 h0 = *(const uint4*)(xroot + (size_t)csr[e + g] * 64 + c8);
            acc8(acc, h0);
            e += 8;
        }
        if (e + g < e1) {
            uint4 h0 = *(const uint4*)(xroot + (size_t)csr[e + g] * 64 + c8);
            acc8(acc, h0);
        }
#pragma unroll
        for (int o = 8; o <= 32; o <<= 1) {
#pragma unroll
            for (int j = 0; j < 8; j++) acc[j] += __shfl_xor(acc[j], o);
        }
        if (lane < 8) {
            __half2 p[4];
#pragma unroll
            for (int j = 0; j < 4; j++)
                p[j] = __floats2half2_rn(acc[2 * j] * sc, acc[2 * j + 1] * sc);
            *(uint4*)&act[nloc * 136 + lane * 8] = *(const uint4*)p;
        }
    }
    __syncthreads();
    if (wid < 4) {
        int row = lane & 15, kg = lane >> 4;
        const _Float16* abase = &act[(wid * 16 + row) * 136 + kg * 8];
        half8 a[4];
#pragma unroll
        for (int kk = 0; kk < 4; kk++) a[kk] = *(const half8*)(abase + kk * 32);
        floatx4 ac[4];
#pragma unroll
        for (int tt = 0; tt < 4; tt++) ac[tt] = (floatx4){0.f, 0.f, 0.f, 0.f};
#pragma unroll
        for (int kk = 0; kk < 4; kk++) {
#pragma unroll
            for (int tt = 0; tt < 4; tt++) {
                half8 b = *(const half8*)&wt[(tt * 16 + row) * 136 + kk * 32 + kg * 8];
                ac[tt] = __builtin_amdgcn_mfma_f32_16x16x32_f16(a[kk], b, ac[tt], 0, 0, 0);
            }
        }
        if (LAST == 0) {
#pragma unroll
            for (int tt = 0; tt < 4; tt++) {
                int col = tt * 16 + row;
                float bias = bs[col];
#pragma unroll
                for (int r = 0; r < 4; r++) {
                    int n = n0 + wid * 16 + kg * 4 + r;
                    if (n < N)
                        xnext[(size_t)n * 64 + col] = __float2half(fmaxf(ac[tt][r] + bias, 0.f));
                }
            }
        } else {
            float wl3v[4], wr3v[4];
#pragma unroll
            for (int tt = 0; tt < 4; tt++) {
                int col = tt * 16 + row;
                wl3v[tt] = Wl3[col];
                wr3v[tt] = Wr3[col];
            }
            float b3 = bl3[0];
            float sp[4], rp[4];
#pragma unroll
            for (int r = 0; r < 4; r++) {
                float spv = 0.f, rpv = 0.f;
#pragma unroll
                for (int tt = 0; tt < 4; tt++) {
                    float v = fmaxf(ac[tt][r] + bs[tt * 16 + row], 0.f);
                    spv += v * wl3v[tt];
                    rpv += v * wr3v[tt];
                }
                sp[r] = spv;
                rp[r] = rpv;
            }
#pragma unroll
            for (int o = 1; o <= 8; o <<= 1) {
#pragma unroll
                for (int r = 0; r < 4; r++) {
                    sp[r] += __shfl_xor(sp[r], o);
                    rp[r] += __shfl_xor(rp[r], o);
                }
            }
            if (row == 0) {
#pragma unroll
                for (int r = 0; r < 4; r++) {
                    int n = n0 + wid * 16 + kg * 4 + r;
                    if (n < N) {
                        s3[n] = sp[r];
                        r3[n] = rp[r] + b3;
                    }
                }
            }
        }
    }
}

__global__ void sage_last_scalar(
    const float* __restrict__ s3, const float* __restrict__ r3, const int* __restrict__ off,
    const int* __restrict__ csr, const float* __restrict__ invd, float* __restrict__ out, int N) {
    int n = blockIdx.x * blockDim.x + threadIdx.x;
    if (n >= N) return;
    int e0 = off[n], e1 = off[n + 1];
    float acc = 0.f;
    int e = e0;
    for (; e + 3 < e1; e += 4) {
        float a0 = s3[csr[e]], a1 = s3[csr[e + 1]], a2 = s3[csr[e + 2]], a3 = s3[csr[e + 3]];
        acc += a0 + a1 + a2 + a3;
    }
    for (; e < e1; e++) acc += s3[csr[e]];
    out[n] = acc * invd[n] + r3[n];
}

// ---------------- launch ----------------

extern "C" void kernel_launch(void* const* d_in, const int* in_sizes, int n_in,
                              void* d_out, int out_size, void* d_ws, size_t ws_size,
                              hipStream_t stream) {
    const float* x0 = (const float*)d_in[0];
    const int* ei = (const int*)d_in[1];
    const float* Wl[4] = {(const float*)d_in[2], (const float*)d_in[5], (const float*)d_in[8],
                          (const float*)d_in[11]};
    const float* bl[4] = {(const float*)d_in[3], (const float*)d_in[6], (const float*)d_in[9],
                          (const float*)d_in[12]};
    const float* Wr[4] = {(const float*)d_in[4], (const float*)d_in[7], (const float*)d_in[10],
                          (const float*)d_in[13]};
    float* out = (float*)d_out;

    const int N = in_sizes[0] / 13;
    const int E = in_sizes[1] / 2;
    const int nbuk = (N + NPB - 1) / NPB;

    char* w = (char*)d_ws;
    auto carve = [&](size_t bytes) {
        void* p = (void*)w;
        w += (bytes + 255) & ~size_t(255);
        return p;
    };
    int* bcnt = (int*)carve((size_t)MAXBUK * 4);
    int* bboff = (int*)carve((size_t)(MAXBUK + 1) * 4);
    int* bcur = (int*)carve((size_t)MAXBUK * 4);
    unsigned int* pairs = (unsigned int*)carve((size_t)E * 4);
    int* csr_off = (int*)carve((size_t)(N + 1) * 4);
    int* csr_src = (int*)carve((size_t)E * 4);
    float* invd = (float*)carve((size_t)N * 4);
    __half* xroot0 = (__half*)carve((size_t)N * 16 * 2);
    __half* xroot1 = (__half*)carve((size_t)N * 64 * 2);
    __half* xroot2 = (__half*)carve((size_t)N * 64 * 2);
    float* s3 = (float*)carve((size_t)N * 4);
    float* r3 = (float*)carve((size_t)N * 4);

    hipMemsetAsync(bcnt, 0, (size_t)MAXBUK * 4, stream);

    bucket_hist<<<1024, 256, 0, stream>>>(ei, E, bcnt, nbuk);
    bucket_scan<<<1, 512, 0, stream>>>(bcnt, bboff, bcur, nbuk, csr_off, N, E);
    partition<<<(E + A3_TILE - 1) / A3_TILE, 256, 0, stream>>>(ei, E, bcur, pairs);
    build_bucket<<<nbuk, 512, 0, stream>>>(pairs, bboff, csr_off, csr_src, invd, N);

    pad_x<<<(N * 16 + NT - 1) / NT, NT, 0, stream>>>(x0, xroot0, N);

    int gblk = (N + 63) / 64;
    fused0<<<gblk, 512, 0, stream>>>(xroot0, csr_off, csr_src, invd,
                                     Wl[0], bl[0], Wr[0], xroot1, N);
    fused_layer<0><<<gblk, 512, 0, stream>>>(xroot1, csr_off, csr_src, invd,
                                             Wl[1], bl[1], Wr[1], xroot2,
                                             nullptr, nullptr, nullptr, nullptr, nullptr, N);
    fused_layer<1><<<gblk, 512, 0, stream>>>(xroot2, csr_off, csr_src, invd,
                                             Wl[2], bl[2], Wr[2], nullptr,
                                             Wl[3], bl[3], Wr[3], s3, r3, N);
    sage_last_scalar<<<(N + NT - 1) / NT, NT, 0, stream>>>(s3, r3, csr_off, csr_src, invd, out, N);
}